// Round 1
// baseline (4328.405 us; speedup 1.0000x reference)
//
#include <hip/hip_runtime.h>

#define HDIM 128

// ---------------------------------------------------------------- copy (float4)
__global__ void copy_f4(float4* __restrict__ dst, const float4* __restrict__ src, int n4) {
    int i = blockIdx.x * blockDim.x + threadIdx.x;
    int stride = gridDim.x * blockDim.x;
    for (; i < n4; i += stride) dst[i] = src[i];
}

// ------------------------------------------------- scatter-add over edges
// one thread per (edge, float4-chunk): 32 threads/edge, 4 atomics/thread
__global__ void scatter_add(float* __restrict__ agg, const float* __restrict__ x,
                            const int* __restrict__ srci, const int* __restrict__ dsti,
                            long total) {
    long i = (long)blockIdx.x * blockDim.x + threadIdx.x;
    if (i >= total) return;
    int e  = (int)(i >> 5);
    int c4 = (int)(i & 31);
    int s = srci[e];
    int d = dsti[e];
    float4 v = *(const float4*)(x + (long)s * HDIM + c4 * 4);
    float* o = agg + (long)d * HDIM + c4 * 4;
    unsafeAtomicAdd(o + 0, v.x);
    unsafeAtomicAdd(o + 1, v.y);
    unsafeAtomicAdd(o + 2, v.z);
    unsafeAtomicAdd(o + 3, v.w);
}

// ------------------------------------------------- fused 128x128 GEMM + BN + ReLU
// out[r][c] = relu((in[r]@W[:,c] + b[c] - m[c]) * g[c]*rsqrt(v[c]+eps) + be[c])
// block: 256 thr; thread t -> row = base + (t>>2), cols [(t&3)*32, +32)
template<bool RELU>
__global__ void mlp128(float* __restrict__ out, const float* __restrict__ in,
                       const float* __restrict__ W, const float* __restrict__ bias,
                       const float* __restrict__ g, const float* __restrict__ be,
                       const float* __restrict__ m, const float* __restrict__ v,
                       int N) {
    __shared__ float Wl[HDIM * HDIM];
    const float4* W4 = (const float4*)W;
    float4* Wl4 = (float4*)Wl;
    #pragma unroll
    for (int i = 0; i < 16; i++) Wl4[threadIdx.x + 256 * i] = W4[threadIdx.x + 256 * i];
    __syncthreads();

    int t = threadIdx.x;
    int row = blockIdx.x * 64 + (t >> 2);
    int c0 = (t & 3) * 32;
    if (row >= N) return;

    float acc[32];
    #pragma unroll
    for (int j = 0; j < 32; j++) acc[j] = 0.f;

    const float4* a4 = (const float4*)(in + (long)row * HDIM);
    for (int k4 = 0; k4 < 32; k4++) {
        float4 a = a4[k4];
        #pragma unroll
        for (int kk = 0; kk < 4; kk++) {
            float av = (kk == 0) ? a.x : (kk == 1) ? a.y : (kk == 2) ? a.z : a.w;
            int base4 = ((k4 * 4 + kk) * HDIM + c0) >> 2;
            #pragma unroll
            for (int j4 = 0; j4 < 8; j4++) {
                float4 w = Wl4[base4 + j4];
                acc[j4 * 4 + 0] += av * w.x;
                acc[j4 * 4 + 1] += av * w.y;
                acc[j4 * 4 + 2] += av * w.z;
                acc[j4 * 4 + 3] += av * w.w;
            }
        }
    }

    float* o = out + (long)row * HDIM + c0;
    #pragma unroll
    for (int j = 0; j < 32; j++) {
        int c = c0 + j;
        float s = g[c] * rsqrtf(v[c] + 1e-5f);
        float val = (acc[j] + bias[c] - m[c]) * s + be[c];
        if (RELU) val = fmaxf(val, 0.f);
        o[j] = val;
    }
}

// ------------------------------------------------- final 128x64 linear (+bias)
// block: 256 thr; thread t -> row = base + (t>>1), cols [(t&1)*32, +32)
__global__ void lin64(float* __restrict__ out, const float* __restrict__ in,
                      const float* __restrict__ W, const float* __restrict__ bias, int N) {
    __shared__ float Wl[HDIM * 64];
    const float4* W4 = (const float4*)W;
    float4* Wl4 = (float4*)Wl;
    #pragma unroll
    for (int i = 0; i < 8; i++) Wl4[threadIdx.x + 256 * i] = W4[threadIdx.x + 256 * i];
    __syncthreads();

    int t = threadIdx.x;
    int row = blockIdx.x * 128 + (t >> 1);
    int c0 = (t & 1) * 32;
    if (row >= N) return;

    float acc[32];
    #pragma unroll
    for (int j = 0; j < 32; j++) acc[j] = 0.f;

    const float4* a4 = (const float4*)(in + (long)row * HDIM);
    for (int k4 = 0; k4 < 32; k4++) {
        float4 a = a4[k4];
        #pragma unroll
        for (int kk = 0; kk < 4; kk++) {
            float av = (kk == 0) ? a.x : (kk == 1) ? a.y : (kk == 2) ? a.z : a.w;
            int base4 = ((k4 * 4 + kk) * 64 + c0) >> 2;
            #pragma unroll
            for (int j4 = 0; j4 < 8; j4++) {
                float4 w = Wl4[base4 + j4];
                acc[j4 * 4 + 0] += av * w.x;
                acc[j4 * 4 + 1] += av * w.y;
                acc[j4 * 4 + 2] += av * w.z;
                acc[j4 * 4 + 3] += av * w.w;
            }
        }
    }

    float* o = out + (long)row * 64 + c0;
    #pragma unroll
    for (int j = 0; j < 32; j++) o[j] = acc[j] + bias[c0 + j];
}

extern "C" void kernel_launch(void* const* d_in, const int* in_sizes, int n_in,
                              void* d_out, int out_size, void* d_ws, size_t ws_size,
                              hipStream_t stream) {
    const float* x  = (const float*)d_in[0];
    const int*   ei = (const int*)d_in[1];
    const int E = in_sizes[1] / 2;
    const int* srci = ei;
    const int* dsti = ei + E;

    const float* W0 = (const float*)d_in[2];
    const float* b0 = (const float*)d_in[3];
    const float* g0 = (const float*)d_in[4];
    const float* be0 = (const float*)d_in[5];
    const float* m0 = (const float*)d_in[6];
    const float* v0 = (const float*)d_in[7];
    const float* W1 = (const float*)d_in[8];
    const float* b1 = (const float*)d_in[9];
    const float* g1 = (const float*)d_in[10];
    const float* be1 = (const float*)d_in[11];
    const float* m1 = (const float*)d_in[12];
    const float* v1 = (const float*)d_in[13];
    const float* W2 = (const float*)d_in[14];
    const float* b2 = (const float*)d_in[15];
    const float* g2 = (const float*)d_in[16];
    const float* be2 = (const float*)d_in[17];
    const float* m2 = (const float*)d_in[18];
    const float* v2 = (const float*)d_in[19];
    const float* W3 = (const float*)d_in[20];
    const float* b3 = (const float*)d_in[21];

    const int N = in_sizes[0] / HDIM;
    float* buf0 = (float*)d_ws;
    float* buf1 = buf0 + (size_t)N * HDIM;
    float* out  = (float*)d_out;

    const int n4 = N * (HDIM / 4);
    const int copyBlocks = (n4 + 255) / 256 < 2048 ? (n4 + 255) / 256 : 2048;
    const long scTotal = (long)E * 32;
    const int scBlocks = (int)((scTotal + 255) / 256);
    const int mlpBlocks = (N + 63) / 64;
    const int linBlocks = (N + 127) / 128;

    // ---- layer 0
    copy_f4<<<copyBlocks, 256, 0, stream>>>((float4*)buf0, (const float4*)x, n4);
    scatter_add<<<scBlocks, 256, 0, stream>>>(buf0, x, srci, dsti, scTotal);
    mlp128<true><<<mlpBlocks, 256, 0, stream>>>(buf1, buf0, W0, b0, g0, be0, m0, v0, N);
    // ---- layer 1
    copy_f4<<<copyBlocks, 256, 0, stream>>>((float4*)buf0, (const float4*)buf1, n4);
    scatter_add<<<scBlocks, 256, 0, stream>>>(buf0, buf1, srci, dsti, scTotal);
    mlp128<true><<<mlpBlocks, 256, 0, stream>>>(buf1, buf0, W1, b1, g1, be1, m1, v1, N);
    // ---- layer 2
    copy_f4<<<copyBlocks, 256, 0, stream>>>((float4*)buf0, (const float4*)buf1, n4);
    scatter_add<<<scBlocks, 256, 0, stream>>>(buf0, buf1, srci, dsti, scTotal);
    mlp128<true><<<mlpBlocks, 256, 0, stream>>>(buf1, buf0, W2, b2, g2, be2, m2, v2, N);
    // ---- final linear
    lin64<<<linBlocks, 256, 0, stream>>>(out, buf1, W3, b3, N);
}

// Round 2
// 614.473 us; speedup vs baseline: 7.0441x; 7.0441x over previous
//
#include <hip/hip_runtime.h>

#define HDIM 128

// ---------------------------------------------------------------- copy (float4)  [fallback path]
__global__ void copy_f4(float4* __restrict__ dst, const float4* __restrict__ src, int n4) {
    int i = blockIdx.x * blockDim.x + threadIdx.x;
    int stride = gridDim.x * blockDim.x;
    for (; i < n4; i += stride) dst[i] = src[i];
}

// ------------------------------------------------- scatter-add over edges [fallback path]
__global__ void scatter_add(float* __restrict__ agg, const float* __restrict__ x,
                            const int* __restrict__ srci, const int* __restrict__ dsti,
                            long total) {
    long i = (long)blockIdx.x * blockDim.x + threadIdx.x;
    if (i >= total) return;
    int e  = (int)(i >> 5);
    int c4 = (int)(i & 31);
    int s = srci[e];
    int d = dsti[e];
    float4 v = *(const float4*)(x + (long)s * HDIM + c4 * 4);
    float* o = agg + (long)d * HDIM + c4 * 4;
    unsafeAtomicAdd(o + 0, v.x);
    unsafeAtomicAdd(o + 1, v.y);
    unsafeAtomicAdd(o + 2, v.z);
    unsafeAtomicAdd(o + 3, v.w);
}

// ------------------------------------------------- CSR build
__global__ void hist_deg(int* __restrict__ deg, const int* __restrict__ dsti, int E) {
    int e = blockIdx.x * blockDim.x + threadIdx.x;
    if (e < E) atomicAdd(&deg[dsti[e]], 1);
}

// single-block exclusive scan of deg[0..N) -> rowptr[0..N], cursor copy
__global__ __launch_bounds__(1024) void scan_rowptr(int* __restrict__ rowptr, int* __restrict__ cursor,
                                                    const int* __restrict__ deg, int N) {
    __shared__ int waveSum[16];
    __shared__ int waveOff[16];
    __shared__ int carry_s;
    int tid = threadIdx.x;
    int lane = tid & 63, wid = tid >> 6;
    if (tid == 0) carry_s = 0;
    __syncthreads();
    int nTiles = (N + 1023) / 1024;
    for (int t = 0; t < nTiles; t++) {
        int i = t * 1024 + tid;
        int v = (i < N) ? deg[i] : 0;
        // wave inclusive scan
        int inc = v;
        #pragma unroll
        for (int s = 1; s < 64; s <<= 1) {
            int n = __shfl_up(inc, s, 64);
            if (lane >= s) inc += n;
        }
        if (lane == 63) waveSum[wid] = inc;
        __syncthreads();
        if (tid == 0) {
            int acc = 0;
            #pragma unroll
            for (int w = 0; w < 16; w++) { waveOff[w] = acc; acc += waveSum[w]; }
            waveSum[15] = acc;  // tile total
        }
        __syncthreads();
        int excl = carry_s + waveOff[wid] + inc - v;
        if (i < N) { rowptr[i] = excl; cursor[i] = excl; }
        int tileTotal = waveSum[15];
        __syncthreads();
        if (tid == 0) carry_s += tileTotal;
        __syncthreads();
    }
    if (tid == 0) rowptr[N] = carry_s;
}

__global__ void fill_csr(int* __restrict__ csr, int* __restrict__ cursor,
                         const int* __restrict__ srci, const int* __restrict__ dsti, int E) {
    int e = blockIdx.x * blockDim.x + threadIdx.x;
    if (e < E) {
        int d = dsti[e];
        int pos = atomicAdd(&cursor[d], 1);
        csr[pos] = srci[e];
    }
}

// ------------------------------------------------- gather aggregation: agg[i] = x[i] + sum_{j in N(i)} x[j]
// 32 threads per node, float4 per thread
__global__ void gather_agg(float* __restrict__ out, const float* __restrict__ x,
                           const int* __restrict__ rowptr, const int* __restrict__ csr, int N) {
    int t = blockIdx.x * blockDim.x + threadIdx.x;
    int node = t >> 5;
    if (node >= N) return;
    int c4 = t & 31;
    const float4* x4 = (const float4*)x;
    float4 acc = x4[(long)node * 32 + c4];
    int s0 = rowptr[node], s1 = rowptr[node + 1];
    for (int k = s0; k < s1; k++) {
        int nb = csr[k];
        float4 v = x4[(long)nb * 32 + c4];
        acc.x += v.x; acc.y += v.y; acc.z += v.z; acc.w += v.w;
    }
    ((float4*)out)[(long)node * 32 + c4] = acc;
}

// ------------------------------------------------- fused 128x128 GEMM + BN + ReLU
template<bool RELU>
__global__ void mlp128(float* __restrict__ out, const float* __restrict__ in,
                       const float* __restrict__ W, const float* __restrict__ bias,
                       const float* __restrict__ g, const float* __restrict__ be,
                       const float* __restrict__ m, const float* __restrict__ v,
                       int N) {
    __shared__ float Wl[HDIM * HDIM];
    const float4* W4 = (const float4*)W;
    float4* Wl4 = (float4*)Wl;
    #pragma unroll
    for (int i = 0; i < 16; i++) Wl4[threadIdx.x + 256 * i] = W4[threadIdx.x + 256 * i];
    __syncthreads();

    int t = threadIdx.x;
    int row = blockIdx.x * 64 + (t >> 2);
    int c0 = (t & 3) * 32;
    if (row >= N) return;

    float acc[32];
    #pragma unroll
    for (int j = 0; j < 32; j++) acc[j] = 0.f;

    const float4* a4 = (const float4*)(in + (long)row * HDIM);
    for (int k4 = 0; k4 < 32; k4++) {
        float4 a = a4[k4];
        #pragma unroll
        for (int kk = 0; kk < 4; kk++) {
            float av = (kk == 0) ? a.x : (kk == 1) ? a.y : (kk == 2) ? a.z : a.w;
            int base4 = ((k4 * 4 + kk) * HDIM + c0) >> 2;
            #pragma unroll
            for (int j4 = 0; j4 < 8; j4++) {
                float4 w = Wl4[base4 + j4];
                acc[j4 * 4 + 0] += av * w.x;
                acc[j4 * 4 + 1] += av * w.y;
                acc[j4 * 4 + 2] += av * w.z;
                acc[j4 * 4 + 3] += av * w.w;
            }
        }
    }

    float* o = out + (long)row * HDIM + c0;
    #pragma unroll
    for (int j = 0; j < 32; j++) {
        int c = c0 + j;
        float s = g[c] * rsqrtf(v[c] + 1e-5f);
        float val = (acc[j] + bias[c] - m[c]) * s + be[c];
        if (RELU) val = fmaxf(val, 0.f);
        o[j] = val;
    }
}

// ------------------------------------------------- final 128x64 linear (+bias)
__global__ void lin64(float* __restrict__ out, const float* __restrict__ in,
                      const float* __restrict__ W, const float* __restrict__ bias, int N) {
    __shared__ float Wl[HDIM * 64];
    const float4* W4 = (const float4*)W;
    float4* Wl4 = (float4*)Wl;
    #pragma unroll
    for (int i = 0; i < 8; i++) Wl4[threadIdx.x + 256 * i] = W4[threadIdx.x + 256 * i];
    __syncthreads();

    int t = threadIdx.x;
    int row = blockIdx.x * 128 + (t >> 1);
    int c0 = (t & 1) * 32;
    if (row >= N) return;

    float acc[32];
    #pragma unroll
    for (int j = 0; j < 32; j++) acc[j] = 0.f;

    const float4* a4 = (const float4*)(in + (long)row * HDIM);
    for (int k4 = 0; k4 < 32; k4++) {
        float4 a = a4[k4];
        #pragma unroll
        for (int kk = 0; kk < 4; kk++) {
            float av = (kk == 0) ? a.x : (kk == 1) ? a.y : (kk == 2) ? a.z : a.w;
            int base4 = ((k4 * 4 + kk) * 64 + c0) >> 2;
            #pragma unroll
            for (int j4 = 0; j4 < 8; j4++) {
                float4 w = Wl4[base4 + j4];
                acc[j4 * 4 + 0] += av * w.x;
                acc[j4 * 4 + 1] += av * w.y;
                acc[j4 * 4 + 2] += av * w.z;
                acc[j4 * 4 + 3] += av * w.w;
            }
        }
    }

    float* o = out + (long)row * 64 + c0;
    #pragma unroll
    for (int j = 0; j < 32; j++) o[j] = acc[j] + bias[c0 + j];
}

extern "C" void kernel_launch(void* const* d_in, const int* in_sizes, int n_in,
                              void* d_out, int out_size, void* d_ws, size_t ws_size,
                              hipStream_t stream) {
    const float* x  = (const float*)d_in[0];
    const int*   ei = (const int*)d_in[1];
    const int E = in_sizes[1] / 2;
    const int* srci = ei;
    const int* dsti = ei + E;

    const float* W0 = (const float*)d_in[2];
    const float* b0 = (const float*)d_in[3];
    const float* g0 = (const float*)d_in[4];
    const float* be0 = (const float*)d_in[5];
    const float* m0 = (const float*)d_in[6];
    const float* v0 = (const float*)d_in[7];
    const float* W1 = (const float*)d_in[8];
    const float* b1 = (const float*)d_in[9];
    const float* g1 = (const float*)d_in[10];
    const float* be1 = (const float*)d_in[11];
    const float* m1 = (const float*)d_in[12];
    const float* v1 = (const float*)d_in[13];
    const float* W2 = (const float*)d_in[14];
    const float* b2 = (const float*)d_in[15];
    const float* g2 = (const float*)d_in[16];
    const float* be2 = (const float*)d_in[17];
    const float* m2 = (const float*)d_in[18];
    const float* v2 = (const float*)d_in[19];
    const float* W3 = (const float*)d_in[20];
    const float* b3 = (const float*)d_in[21];

    const int N = in_sizes[0] / HDIM;
    float* buf0 = (float*)d_ws;
    float* buf1 = buf0 + (size_t)N * HDIM;
    char*  extra = (char*)(buf1 + (size_t)N * HDIM);
    int* rowptr = (int*)extra;             // N+1
    int* cursor = rowptr + (N + 1);        // N
    int* csr    = cursor + N;              // E
    size_t needed = (size_t)N * HDIM * 4 * 2 + ((size_t)N * 2 + 1 + E) * 4;

    float* out = (float*)d_out;

    const int mlpBlocks = (N + 63) / 64;
    const int linBlocks = (N + 127) / 128;
    const int edgeBlocks = (E + 255) / 256;
    const int gatherBlocks = (N * 32 + 255) / 256;

    if (ws_size >= needed) {
        // ---- build CSR (dst-sorted adjacency), once per launch
        hipMemsetAsync(rowptr, 0, (size_t)(N + 1) * 4, stream);   // reuse rowptr as deg
        hist_deg<<<edgeBlocks, 256, 0, stream>>>(rowptr, dsti, E);
        // scan reads deg (=rowptr) and overwrites it in-place tile-by-tile: need a copy to be safe.
        // Use cursor as the deg source instead: copy deg->csr area? Simpler: scan from rowptr into
        // cursor-as-rowptr would alias. Use separate deg buffer at end of csr (E ints >= N+1? yes E>>N).
        // Actually scan below reads deg[i] then writes rowptr[i] at the same index AFTER reading; but
        // later tiles never re-read earlier entries, and i-th read happens before i-th write. Safe in-place.
        scan_rowptr<<<1, 1024, 0, stream>>>(rowptr, cursor, rowptr, N);
        fill_csr<<<edgeBlocks, 256, 0, stream>>>(csr, cursor, srci, dsti, E);

        // ---- layer 0
        gather_agg<<<gatherBlocks, 256, 0, stream>>>(buf0, x, rowptr, csr, N);
        mlp128<true><<<mlpBlocks, 256, 0, stream>>>(buf1, buf0, W0, b0, g0, be0, m0, v0, N);
        // ---- layer 1
        gather_agg<<<gatherBlocks, 256, 0, stream>>>(buf0, buf1, rowptr, csr, N);
        mlp128<true><<<mlpBlocks, 256, 0, stream>>>(buf1, buf0, W1, b1, g1, be1, m1, v1, N);
        // ---- layer 2
        gather_agg<<<gatherBlocks, 256, 0, stream>>>(buf0, buf1, rowptr, csr, N);
        mlp128<true><<<mlpBlocks, 256, 0, stream>>>(buf1, buf0, W2, b2, g2, be2, m2, v2, N);
        // ---- final linear
        lin64<<<linBlocks, 256, 0, stream>>>(out, buf1, W3, b3, N);
    } else {
        // fallback: atomic scatter path (R1 behavior)
        const int n4 = N * (HDIM / 4);
        const int copyBlocks = (n4 + 255) / 256 < 2048 ? (n4 + 255) / 256 : 2048;
        const long scTotal = (long)E * 32;
        const int scBlocks = (int)((scTotal + 255) / 256);
        copy_f4<<<copyBlocks, 256, 0, stream>>>((float4*)buf0, (const float4*)x, n4);
        scatter_add<<<scBlocks, 256, 0, stream>>>(buf0, x, srci, dsti, scTotal);
        mlp128<true><<<mlpBlocks, 256, 0, stream>>>(buf1, buf0, W0, b0, g0, be0, m0, v0, N);
        copy_f4<<<copyBlocks, 256, 0, stream>>>((float4*)buf0, (const float4*)buf1, n4);
        scatter_add<<<scBlocks, 256, 0, stream>>>(buf0, buf1, srci, dsti, scTotal);
        mlp128<true><<<mlpBlocks, 256, 0, stream>>>(buf1, buf0, W1, b1, g1, be1, m1, v1, N);
        copy_f4<<<copyBlocks, 256, 0, stream>>>((float4*)buf0, (const float4*)buf1, n4);
        scatter_add<<<scBlocks, 256, 0, stream>>>(buf0, buf1, srci, dsti, scTotal);
        mlp128<true><<<mlpBlocks, 256, 0, stream>>>(buf1, buf0, W2, b2, g2, be2, m2, v2, N);
        lin64<<<linBlocks, 256, 0, stream>>>(out, buf1, W3, b3, N);
    }
}

// Round 3
// 392.565 us; speedup vs baseline: 11.0259x; 1.5653x over previous
//
#include <hip/hip_runtime.h>

#define HDIM 128

typedef __attribute__((ext_vector_type(8))) short short8;
typedef __attribute__((ext_vector_type(4))) float f32x4;

__device__ __forceinline__ short f2bf(float f) {
    union { float f; unsigned u; } x; x.f = f;
    unsigned r = x.u + 0x7FFF + ((x.u >> 16) & 1);   // round-to-nearest-even
    return (short)(r >> 16);
}

// ------------------------------------------------- CSR build
__global__ void hist_deg(int* __restrict__ deg, const int* __restrict__ dsti, int E) {
    int e = blockIdx.x * blockDim.x + threadIdx.x;
    if (e < E) atomicAdd(&deg[dsti[e]], 1);
}

__global__ __launch_bounds__(1024) void scan_rowptr(int* __restrict__ rowptr, int* __restrict__ cursor,
                                                    const int* __restrict__ deg, int N) {
    __shared__ int waveSum[16];
    __shared__ int waveOff[16];
    __shared__ int carry_s;
    int tid = threadIdx.x;
    int lane = tid & 63, wid = tid >> 6;
    if (tid == 0) carry_s = 0;
    __syncthreads();
    int nTiles = (N + 1023) / 1024;
    for (int t = 0; t < nTiles; t++) {
        int i = t * 1024 + tid;
        int v = (i < N) ? deg[i] : 0;
        int inc = v;
        #pragma unroll
        for (int s = 1; s < 64; s <<= 1) {
            int n = __shfl_up(inc, s, 64);
            if (lane >= s) inc += n;
        }
        if (lane == 63) waveSum[wid] = inc;
        __syncthreads();
        if (tid == 0) {
            int acc = 0;
            #pragma unroll
            for (int w = 0; w < 16; w++) { waveOff[w] = acc; acc += waveSum[w]; }
            waveSum[15] = acc;
        }
        __syncthreads();
        int excl = carry_s + waveOff[wid] + inc - v;
        if (i < N) { rowptr[i] = excl; cursor[i] = excl; }
        int tileTotal = waveSum[15];
        __syncthreads();
        if (tid == 0) carry_s += tileTotal;
        __syncthreads();
    }
    if (tid == 0) rowptr[N] = carry_s;
}

__global__ void fill_csr(int* __restrict__ csr, int* __restrict__ cursor,
                         const int* __restrict__ srci, const int* __restrict__ dsti, int E) {
    int e = blockIdx.x * blockDim.x + threadIdx.x;
    if (e < E) {
        int d = dsti[e];
        int pos = atomicAdd(&cursor[d], 1);
        csr[pos] = srci[e];
    }
}

// ------------------------------------------------- gather aggregation (2-deep ILP)
__global__ void gather_agg(float* __restrict__ out, const float* __restrict__ x,
                           const int* __restrict__ rowptr, const int* __restrict__ csr, int N) {
    int t = blockIdx.x * blockDim.x + threadIdx.x;
    int node = t >> 5;
    if (node >= N) return;
    int c4 = t & 31;
    const float4* x4 = (const float4*)x;
    float4 acc = x4[(long)node * 32 + c4];
    int s0 = rowptr[node], s1 = rowptr[node + 1];
    int k = s0;
    for (; k + 2 <= s1; k += 2) {
        int n0 = csr[k], n1 = csr[k + 1];
        float4 v0 = x4[(long)n0 * 32 + c4];
        float4 v1 = x4[(long)n1 * 32 + c4];
        acc.x += v0.x + v1.x;
        acc.y += v0.y + v1.y;
        acc.z += v0.z + v1.z;
        acc.w += v0.w + v1.w;
    }
    if (k < s1) {
        int n0 = csr[k];
        float4 v0 = x4[(long)n0 * 32 + c4];
        acc.x += v0.x; acc.y += v0.y; acc.z += v0.z; acc.w += v0.w;
    }
    ((float4*)out)[(long)node * 32 + c4] = acc;
}

// ------------------------------------------------- weight pack: W[K][C] fp32 -> B-fragment order bf16
// Wp[(nt*4+ks)*64 + lane] = 8 bf16: W[ks*32+(lane>>4)*8 + j][nt*16+(lane&15)]
__global__ void pack_w(short* __restrict__ Wp, const float* __restrict__ W, int C, int NT) {
    int tid = blockIdx.x * blockDim.x + threadIdx.x;
    if (tid >= NT * 4 * 64) return;
    int lane = tid & 63;
    int ks = (tid >> 6) & 3;
    int nt = tid >> 8;
    int n = nt * 16 + (lane & 15);
    int k0 = ks * 32 + ((lane >> 4) & 3) * 8;
    short8 v;
    #pragma unroll
    for (int j = 0; j < 8; j++) v[j] = f2bf(W[(long)(k0 + j) * C + n]);
    ((short8*)Wp)[tid] = v;
}

// scale/offset fold of BN+bias: out = acc*scale[c] + offset[c]
__global__ void prep_scales(float* __restrict__ scale, float* __restrict__ offset,
                            const float* __restrict__ bias, const float* __restrict__ g,
                            const float* __restrict__ be, const float* __restrict__ m,
                            const float* __restrict__ v, int C, int hasBN) {
    int c = blockIdx.x * blockDim.x + threadIdx.x;
    if (c >= C) return;
    if (hasBN) {
        float s = g[c] * rsqrtf(v[c] + 1e-5f);
        scale[c] = s;
        offset[c] = (bias[c] - m[c]) * s + be[c];
    } else {
        scale[c] = 1.f;
        offset[c] = bias[c];
    }
}

// ------------------------------------------------- MFMA GEMM + fused scale/offset (+ReLU)
// block = 256 thr = 4 waves; wave handles 16 rows x (NT*16) cols, K=128
template<int NT, bool RELU>
__global__ __launch_bounds__(256) void mlp_mfma(float* __restrict__ out, const float* __restrict__ in,
                                                const short* __restrict__ Wp,
                                                const float* __restrict__ scale,
                                                const float* __restrict__ offset, int N) {
    int lane = threadIdx.x & 63;
    int wid = threadIdx.x >> 6;
    int row0 = blockIdx.x * 64 + wid * 16;
    if (row0 >= N) return;

    int arow = row0 + (lane & 15);
    if (arow >= N) arow = N - 1;                      // clamp (stores are masked)
    const float* ap = in + (long)arow * HDIM + ((lane >> 4) & 3) * 8;

    short8 a[4];
    #pragma unroll
    for (int ks = 0; ks < 4; ks++) {
        float4 lo = *(const float4*)(ap + ks * 32);
        float4 hi = *(const float4*)(ap + ks * 32 + 4);
        short8 t;
        t[0] = f2bf(lo.x); t[1] = f2bf(lo.y); t[2] = f2bf(lo.z); t[3] = f2bf(lo.w);
        t[4] = f2bf(hi.x); t[5] = f2bf(hi.y); t[6] = f2bf(hi.z); t[7] = f2bf(hi.w);
        a[ks] = t;
    }

    const short8* bp = (const short8*)Wp + lane;
    #pragma unroll
    for (int nt = 0; nt < NT; nt++) {
        f32x4 acc = {0.f, 0.f, 0.f, 0.f};
        short8 b0 = bp[(nt * 4 + 0) * 64];
        short8 b1 = bp[(nt * 4 + 1) * 64];
        short8 b2 = bp[(nt * 4 + 2) * 64];
        short8 b3 = bp[(nt * 4 + 3) * 64];
        acc = __builtin_amdgcn_mfma_f32_16x16x32_bf16(a[0], b0, acc, 0, 0, 0);
        acc = __builtin_amdgcn_mfma_f32_16x16x32_bf16(a[1], b1, acc, 0, 0, 0);
        acc = __builtin_amdgcn_mfma_f32_16x16x32_bf16(a[2], b2, acc, 0, 0, 0);
        acc = __builtin_amdgcn_mfma_f32_16x16x32_bf16(a[3], b3, acc, 0, 0, 0);

        int c = nt * 16 + (lane & 15);
        float s = scale[c], o = offset[c];
        int rbase = row0 + ((lane >> 4) & 3) * 4;
        #pragma unroll
        for (int r = 0; r < 4; r++) {
            int rr = rbase + r;
            if (rr < N) {
                float val = acc[r] * s + o;
                if (RELU) val = fmaxf(val, 0.f);
                out[(long)rr * (NT * 16) + c] = val;
            }
        }
    }
}

extern "C" void kernel_launch(void* const* d_in, const int* in_sizes, int n_in,
                              void* d_out, int out_size, void* d_ws, size_t ws_size,
                              hipStream_t stream) {
    const float* x  = (const float*)d_in[0];
    const int*   ei = (const int*)d_in[1];
    const int E = in_sizes[1] / 2;
    const int* srci = ei;
    const int* dsti = ei + E;

    const float* W0 = (const float*)d_in[2];
    const float* b0 = (const float*)d_in[3];
    const float* g0 = (const float*)d_in[4];
    const float* be0 = (const float*)d_in[5];
    const float* m0 = (const float*)d_in[6];
    const float* v0 = (const float*)d_in[7];
    const float* W1 = (const float*)d_in[8];
    const float* b1 = (const float*)d_in[9];
    const float* g1 = (const float*)d_in[10];
    const float* be1 = (const float*)d_in[11];
    const float* m1 = (const float*)d_in[12];
    const float* v1 = (const float*)d_in[13];
    const float* W2 = (const float*)d_in[14];
    const float* b2 = (const float*)d_in[15];
    const float* g2 = (const float*)d_in[16];
    const float* be2 = (const float*)d_in[17];
    const float* m2 = (const float*)d_in[18];
    const float* v2 = (const float*)d_in[19];
    const float* W3 = (const float*)d_in[20];
    const float* b3 = (const float*)d_in[21];

    const int N = in_sizes[0] / HDIM;
    float* out = (float*)d_out;

    // ---- workspace layout
    float* buf0 = (float*)d_ws;
    float* buf1 = buf0 + (size_t)N * HDIM;
    int* rowptr = (int*)(buf1 + (size_t)N * HDIM);   // N+1
    int* cursor = rowptr + (N + 1);                  // N
    int* csr    = cursor + N;                        // E
    short* Wp0  = (short*)(csr + E);                 // 8*4*64*8 = 16384 shorts
    short* Wp1  = Wp0 + 16384;
    short* Wp2  = Wp1 + 16384;
    short* Wp3  = Wp2 + 16384;                       // 4*4*64*8 = 8192 shorts
    float* sc0  = (float*)(Wp3 + 8192);              // 4 x (scale,offset) of 128
    float* of0  = sc0 + HDIM;
    float* sc1  = of0 + HDIM;
    float* of1  = sc1 + HDIM;
    float* sc2  = of1 + HDIM;
    float* of2  = sc2 + HDIM;
    float* sc3  = of2 + HDIM;
    float* of3  = sc3 + HDIM;

    const int mlpBlocks = (N + 63) / 64;
    const int edgeBlocks = (E + 255) / 256;
    const int gatherBlocks = (N * 32 + 255) / 256;

    // ---- prep: CSR + packed weights + folded scales (all tiny or edge-linear)
    hipMemsetAsync(rowptr, 0, (size_t)(N + 1) * 4, stream);
    hist_deg<<<edgeBlocks, 256, 0, stream>>>(rowptr, dsti, E);
    scan_rowptr<<<1, 1024, 0, stream>>>(rowptr, cursor, rowptr, N);
    fill_csr<<<edgeBlocks, 256, 0, stream>>>(csr, cursor, srci, dsti, E);

    pack_w<<<8, 256, 0, stream>>>(Wp0, W0, 128, 8);
    pack_w<<<8, 256, 0, stream>>>(Wp1, W1, 128, 8);
    pack_w<<<8, 256, 0, stream>>>(Wp2, W2, 128, 8);
    pack_w<<<4, 256, 0, stream>>>(Wp3, W3, 64, 4);
    prep_scales<<<1, 128, 0, stream>>>(sc0, of0, b0, g0, be0, m0, v0, 128, 1);
    prep_scales<<<1, 128, 0, stream>>>(sc1, of1, b1, g1, be1, m1, v1, 128, 1);
    prep_scales<<<1, 128, 0, stream>>>(sc2, of2, b2, g2, be2, m2, v2, 128, 1);
    prep_scales<<<1, 128, 0, stream>>>(sc3, of3, b3, b3, b3, b3, b3, 64, 0);

    // ---- layer 0
    gather_agg<<<gatherBlocks, 256, 0, stream>>>(buf0, x, rowptr, csr, N);
    mlp_mfma<8, true><<<mlpBlocks, 256, 0, stream>>>(buf1, buf0, Wp0, sc0, of0, N);
    // ---- layer 1
    gather_agg<<<gatherBlocks, 256, 0, stream>>>(buf0, buf1, rowptr, csr, N);
    mlp_mfma<8, true><<<mlpBlocks, 256, 0, stream>>>(buf1, buf0, Wp1, sc1, of1, N);
    // ---- layer 2
    gather_agg<<<gatherBlocks, 256, 0, stream>>>(buf0, buf1, rowptr, csr, N);
    mlp_mfma<8, true><<<mlpBlocks, 256, 0, stream>>>(buf1, buf0, Wp2, sc2, of2, N);
    // ---- final linear -> d_out
    mlp_mfma<4, false><<<mlpBlocks, 256, 0, stream>>>(out, buf1, Wp3, sc3, of3, N);
}

// Round 4
// 271.993 us; speedup vs baseline: 15.9137x; 1.4433x over previous
//
#include <hip/hip_runtime.h>

#define HDIM 128

typedef __attribute__((ext_vector_type(8))) short short8;
typedef __attribute__((ext_vector_type(4))) float f32x4;

__device__ __forceinline__ short f2bf(float f) {
    union { float f; unsigned u; } x; x.f = f;
    unsigned r = x.u + 0x7FFF + ((x.u >> 16) & 1);   // RNE
    return (short)(r >> 16);
}
__device__ __forceinline__ float bf2f(short s) {
    union { unsigned u; float f; } x;
    x.u = ((unsigned)(unsigned short)s) << 16;
    return x.f;
}

// ------------------------------------------------- fp32 -> bf16 convert
__global__ void cvt_bf16(short* __restrict__ dst, const float* __restrict__ src, int n) {
    int i = (blockIdx.x * blockDim.x + threadIdx.x) * 4;
    int stride = gridDim.x * blockDim.x * 4;
    for (; i < n; i += stride) {
        float4 v = *(const float4*)(src + i);
        short4 o;
        o.x = f2bf(v.x); o.y = f2bf(v.y); o.z = f2bf(v.z); o.w = f2bf(v.w);
        *(short4*)(dst + i) = o;
    }
}

// ------------------------------------------------- CSR build
__global__ void hist_deg(int* __restrict__ deg, const int* __restrict__ dsti, int E) {
    int e = blockIdx.x * blockDim.x + threadIdx.x;
    if (e < E) atomicAdd(&deg[dsti[e]], 1);
}

// single-block exclusive scan, 4 elems/thread (int4)
__global__ __launch_bounds__(1024) void scan_rowptr(int* __restrict__ rowptr, int* __restrict__ cursor,
                                                    const int* __restrict__ deg, int N) {
    __shared__ int waveSum[16];
    __shared__ int waveOff[16];
    __shared__ int carry_s;
    int tid = threadIdx.x;
    int lane = tid & 63, wid = tid >> 6;
    if (tid == 0) carry_s = 0;
    __syncthreads();
    int nTiles = (N + 4095) / 4096;
    for (int tt = 0; tt < nTiles; tt++) {
        int base = tt * 4096 + tid * 4;
        int4 d = {0, 0, 0, 0};
        if (base + 3 < N) d = *(const int4*)(deg + base);
        else {
            if (base < N) d.x = deg[base];
            if (base + 1 < N) d.y = deg[base + 1];
            if (base + 2 < N) d.z = deg[base + 2];
        }
        int tot = d.x + d.y + d.z + d.w;
        int inc = tot;
        #pragma unroll
        for (int s = 1; s < 64; s <<= 1) {
            int n = __shfl_up(inc, s, 64);
            if (lane >= s) inc += n;
        }
        if (lane == 63) waveSum[wid] = inc;
        __syncthreads();
        if (tid == 0) {
            int acc = 0;
            #pragma unroll
            for (int w = 0; w < 16; w++) { waveOff[w] = acc; acc += waveSum[w]; }
            waveSum[15] = acc;  // tile total
        }
        __syncthreads();
        int excl = carry_s + waveOff[wid] + inc - tot;
        int e0 = excl, e1 = excl + d.x, e2 = e1 + d.y, e3 = e2 + d.z;
        if (base + 3 < N) {
            int4 o = {e0, e1, e2, e3};
            *(int4*)(rowptr + base) = o;
            *(int4*)(cursor + base) = o;
        } else {
            if (base < N)     { rowptr[base] = e0;     cursor[base] = e0; }
            if (base + 1 < N) { rowptr[base + 1] = e1; cursor[base + 1] = e1; }
            if (base + 2 < N) { rowptr[base + 2] = e2; cursor[base + 2] = e2; }
        }
        int tileTotal = waveSum[15];
        __syncthreads();
        if (tid == 0) carry_s += tileTotal;
        __syncthreads();
    }
    if (tid == 0) rowptr[N] = carry_s;
}

__global__ void fill_csr(int* __restrict__ csr, int* __restrict__ cursor,
                         const int* __restrict__ srci, const int* __restrict__ dsti, int E) {
    int e = blockIdx.x * blockDim.x + threadIdx.x;
    if (e < E) {
        int d = dsti[e];
        int pos = atomicAdd(&cursor[d], 1);
        csr[pos] = srci[e];
    }
}

// ------------------------------------------------- weight pack (verified in R3)
// Wp[(nt*4+ks)*64 + lane] = 8 bf16: W[ks*32+(lane>>4)*8 + j][nt*16+(lane&15)]
__global__ void pack_w(short* __restrict__ Wp, const float* __restrict__ W, int C, int NT) {
    int tid = blockIdx.x * blockDim.x + threadIdx.x;
    if (tid >= NT * 4 * 64) return;
    int lane = tid & 63;
    int ks = (tid >> 6) & 3;
    int nt = tid >> 8;
    int n = nt * 16 + (lane & 15);
    int k0 = ks * 32 + ((lane >> 4) & 3) * 8;
    short8 v;
    #pragma unroll
    for (int j = 0; j < 8; j++) v[j] = f2bf(W[(long)(k0 + j) * C + n]);
    ((short8*)Wp)[tid] = v;
}

__global__ void prep_scales(float* __restrict__ scale, float* __restrict__ offset,
                            const float* __restrict__ bias, const float* __restrict__ g,
                            const float* __restrict__ be, const float* __restrict__ m,
                            const float* __restrict__ v, int C, int hasBN) {
    int c = blockIdx.x * blockDim.x + threadIdx.x;
    if (c >= C) return;
    if (hasBN) {
        float s = g[c] * rsqrtf(v[c] + 1e-5f);
        scale[c] = s;
        offset[c] = (bias[c] - m[c]) * s + be[c];
    } else {
        scale[c] = 1.f;
        offset[c] = bias[c];
    }
}

// ------------------------------------------------- fused GIN layer:
//   gather (bf16, CSR) -> LDS tile (swizzled) -> MFMA GEMM + BN + ReLU
//   FINAL=false: write bf16 activations [N][128]
//   FINAL=true : write h to own LDS stripe, second GEMM with Wp2 -> fp32 out [N][64]
template<bool FINAL>
__global__ __launch_bounds__(256) void gin_layer(
        short* __restrict__ outb, float* __restrict__ outf,
        const short* __restrict__ xp,
        const int* __restrict__ rowptr, const int* __restrict__ csr,
        const short* __restrict__ Wp,
        const float* __restrict__ scale, const float* __restrict__ offset,
        const short* __restrict__ Wp2,
        const float* __restrict__ scale2, const float* __restrict__ offset2,
        int N) {
    __shared__ short As[64 * HDIM];   // 16 KB, [64 rows][256 B], XOR-swizzled 16B granules
    const int t = threadIdx.x;
    const int row0 = blockIdx.x * 64;

    // ---- Phase A: gather agg = x[i] + sum_j x[j] into LDS (bf16)
    const short8* xp8 = (const short8*)xp;   // 16 x 16B chunks per row
    #pragma unroll
    for (int g = 0; g < 4; g++) {
        int rl = g * 16 + (t >> 4);          // local row 0..63
        int chunk = t & 15;
        int node = row0 + rl;
        float facc[8];
        if (node < N) {
            short8 id = xp8[(long)node * 16 + chunk];
            #pragma unroll
            for (int j = 0; j < 8; j++) facc[j] = bf2f(id[j]);
            int s0 = rowptr[node], s1 = rowptr[node + 1];
            int k = s0;
            for (; k + 2 <= s1; k += 2) {
                int n0 = csr[k], n1 = csr[k + 1];
                short8 v0 = xp8[(long)n0 * 16 + chunk];
                short8 v1 = xp8[(long)n1 * 16 + chunk];
                #pragma unroll
                for (int j = 0; j < 8; j++) facc[j] += bf2f(v0[j]) + bf2f(v1[j]);
            }
            if (k < s1) {
                short8 v0 = xp8[(long)csr[k] * 16 + chunk];
                #pragma unroll
                for (int j = 0; j < 8; j++) facc[j] += bf2f(v0[j]);
            }
        } else {
            #pragma unroll
            for (int j = 0; j < 8; j++) facc[j] = 0.f;
        }
        short8 o;
        #pragma unroll
        for (int j = 0; j < 8; j++) o[j] = f2bf(facc[j]);
        int baddr = (rl * 256 + chunk * 16) ^ ((rl & 7) << 4);
        *(short8*)((char*)As + baddr) = o;
    }
    __syncthreads();

    // ---- Phase B: GEMM1 (K=128), A from LDS, B packed from L2
    const int lane = t & 63, w = t >> 6;
    const int rl0 = w * 16 + (lane & 15);    // A-frag row (local)
    const int hi = (lane >> 4) & 3;
    short8 a[4];
    #pragma unroll
    for (int ks = 0; ks < 4; ks++) {
        int baddr = (rl0 * 256 + ks * 64 + hi * 16) ^ ((rl0 & 7) << 4);
        a[ks] = *(const short8*)((const char*)As + baddr);
    }
    const short8* bp = (const short8*)Wp + lane;
    const int c = lane & 15;
    const int rb = hi * 4;                   // C-frag local row base

    #pragma unroll
    for (int nt = 0; nt < 8; nt++) {
        f32x4 acc = {0.f, 0.f, 0.f, 0.f};
        short8 b0 = bp[(nt * 4 + 0) * 64];
        short8 b1 = bp[(nt * 4 + 1) * 64];
        short8 b2 = bp[(nt * 4 + 2) * 64];
        short8 b3 = bp[(nt * 4 + 3) * 64];
        acc = __builtin_amdgcn_mfma_f32_16x16x32_bf16(a[0], b0, acc, 0, 0, 0);
        acc = __builtin_amdgcn_mfma_f32_16x16x32_bf16(a[1], b1, acc, 0, 0, 0);
        acc = __builtin_amdgcn_mfma_f32_16x16x32_bf16(a[2], b2, acc, 0, 0, 0);
        acc = __builtin_amdgcn_mfma_f32_16x16x32_bf16(a[3], b3, acc, 0, 0, 0);
        int cc = nt * 16 + c;
        float s = scale[cc], o = offset[cc];
        if (!FINAL) {
            #pragma unroll
            for (int r = 0; r < 4; r++) {
                int rr = row0 + w * 16 + rb + r;
                if (rr < N) {
                    float val = fmaxf(acc[r] * s + o, 0.f);
                    outb[(long)rr * HDIM + cc] = f2bf(val);
                }
            }
        } else {
            // write h (bf16) back into own wave's LDS stripe (wave-local: no barrier)
            #pragma unroll
            for (int r = 0; r < 4; r++) {
                int rloc = w * 16 + rb + r;
                float val = fmaxf(acc[r] * s + o, 0.f);
                int baddr = (rloc * 256 + cc * 2) ^ ((rloc & 7) << 4);
                *(short*)((char*)As + baddr) = f2bf(val);
            }
        }
    }

    if (FINAL) {
        // ---- GEMM2: out = h @ W3 + b3   (A2 from own stripe, NT2=4)
        short8 a2[4];
        #pragma unroll
        for (int ks = 0; ks < 4; ks++) {
            int baddr = (rl0 * 256 + ks * 64 + hi * 16) ^ ((rl0 & 7) << 4);
            a2[ks] = *(const short8*)((const char*)As + baddr);
        }
        const short8* bp2 = (const short8*)Wp2 + lane;
        #pragma unroll
        for (int nt = 0; nt < 4; nt++) {
            f32x4 acc = {0.f, 0.f, 0.f, 0.f};
            short8 b0 = bp2[(nt * 4 + 0) * 64];
            short8 b1 = bp2[(nt * 4 + 1) * 64];
            short8 b2 = bp2[(nt * 4 + 2) * 64];
            short8 b3v = bp2[(nt * 4 + 3) * 64];
            acc = __builtin_amdgcn_mfma_f32_16x16x32_bf16(a2[0], b0, acc, 0, 0, 0);
            acc = __builtin_amdgcn_mfma_f32_16x16x32_bf16(a2[1], b1, acc, 0, 0, 0);
            acc = __builtin_amdgcn_mfma_f32_16x16x32_bf16(a2[2], b2, acc, 0, 0, 0);
            acc = __builtin_amdgcn_mfma_f32_16x16x32_bf16(a2[3], b3v, acc, 0, 0, 0);
            int cc = nt * 16 + c;
            float s2 = scale2[cc], o2 = offset2[cc];
            #pragma unroll
            for (int r = 0; r < 4; r++) {
                int rr = row0 + w * 16 + rb + r;
                if (rr < N) outf[(long)rr * 64 + cc] = acc[r] * s2 + o2;
            }
        }
    }
}

extern "C" void kernel_launch(void* const* d_in, const int* in_sizes, int n_in,
                              void* d_out, int out_size, void* d_ws, size_t ws_size,
                              hipStream_t stream) {
    const float* x  = (const float*)d_in[0];
    const int*   ei = (const int*)d_in[1];
    const int E = in_sizes[1] / 2;
    const int* srci = ei;
    const int* dsti = ei + E;

    const float* W0 = (const float*)d_in[2];
    const float* b0 = (const float*)d_in[3];
    const float* g0 = (const float*)d_in[4];
    const float* be0 = (const float*)d_in[5];
    const float* m0 = (const float*)d_in[6];
    const float* v0 = (const float*)d_in[7];
    const float* W1 = (const float*)d_in[8];
    const float* b1 = (const float*)d_in[9];
    const float* g1 = (const float*)d_in[10];
    const float* be1 = (const float*)d_in[11];
    const float* m1 = (const float*)d_in[12];
    const float* v1 = (const float*)d_in[13];
    const float* W2 = (const float*)d_in[14];
    const float* b2 = (const float*)d_in[15];
    const float* g2 = (const float*)d_in[16];
    const float* be2 = (const float*)d_in[17];
    const float* m2 = (const float*)d_in[18];
    const float* v2 = (const float*)d_in[19];
    const float* W3 = (const float*)d_in[20];
    const float* b3 = (const float*)d_in[21];

    const int N = in_sizes[0] / HDIM;
    float* out = (float*)d_out;

    // ---- workspace layout (16B-aligned sections)
    short* ba = (short*)d_ws;                        // N*128 bf16
    short* bb = ba + (size_t)N * HDIM;               // N*128 bf16
    int* rowptr = (int*)(bb + (size_t)N * HDIM);     // N+1 (padded to /4)
    int* cursor = rowptr + ((N + 4) & ~3);           // N
    int* csr    = cursor + N;                        // E
    uintptr_t p = ((uintptr_t)(csr + E) + 63) & ~(uintptr_t)63;
    short* Wp0  = (short*)p;                         // 16384 shorts
    short* Wp1  = Wp0 + 16384;
    short* Wp2  = Wp1 + 16384;
    short* Wp3  = Wp2 + 16384;                       // 8192 shorts
    float* sc0  = (float*)(Wp3 + 8192);
    float* of0  = sc0 + HDIM;
    float* sc1  = of0 + HDIM;
    float* of1  = sc1 + HDIM;
    float* sc2  = of1 + HDIM;
    float* of2  = sc2 + HDIM;
    float* sc3  = of2 + HDIM;
    float* of3  = sc3 + HDIM;

    const int edgeBlocks = (E + 255) / 256;
    const int layerBlocks = (N + 63) / 64;
    const int nElem = N * HDIM;
    int cvtBlocks = (nElem / 4 + 255) / 256; if (cvtBlocks > 2048) cvtBlocks = 2048;

    // ---- prep
    cvt_bf16<<<cvtBlocks, 256, 0, stream>>>(ba, x, nElem);
    hipMemsetAsync(rowptr, 0, (size_t)(N + 1) * 4, stream);
    hist_deg<<<edgeBlocks, 256, 0, stream>>>(rowptr, dsti, E);
    scan_rowptr<<<1, 1024, 0, stream>>>(rowptr, cursor, rowptr, N);
    fill_csr<<<edgeBlocks, 256, 0, stream>>>(csr, cursor, srci, dsti, E);

    pack_w<<<8, 256, 0, stream>>>(Wp0, W0, 128, 8);
    pack_w<<<8, 256, 0, stream>>>(Wp1, W1, 128, 8);
    pack_w<<<8, 256, 0, stream>>>(Wp2, W2, 128, 8);
    pack_w<<<4, 256, 0, stream>>>(Wp3, W3, 64, 4);
    prep_scales<<<1, 128, 0, stream>>>(sc0, of0, b0, g0, be0, m0, v0, 128, 1);
    prep_scales<<<1, 128, 0, stream>>>(sc1, of1, b1, g1, be1, m1, v1, 128, 1);
    prep_scales<<<1, 128, 0, stream>>>(sc2, of2, b2, g2, be2, m2, v2, 128, 1);
    prep_scales<<<1, 128, 0, stream>>>(sc3, of3, b3, b3, b3, b3, b3, 64, 0);

    // ---- 3 fused layers (last one also applies W3 -> fp32 out)
    gin_layer<false><<<layerBlocks, 256, 0, stream>>>(
        bb, nullptr, ba, rowptr, csr, Wp0, sc0, of0, nullptr, nullptr, nullptr, N);
    gin_layer<false><<<layerBlocks, 256, 0, stream>>>(
        ba, nullptr, bb, rowptr, csr, Wp1, sc1, of1, nullptr, nullptr, nullptr, N);
    gin_layer<true><<<layerBlocks, 256, 0, stream>>>(
        nullptr, out, ba, rowptr, csr, Wp2, sc2, of2, Wp3, sc3, of3, N);
}

// Round 5
// 190.876 us; speedup vs baseline: 22.6765x; 1.4250x over previous
//
#include <hip/hip_runtime.h>

#define HDIM 128
#define CAP 64   // padded-CSR slots per node; deg ~ Poisson(16), P(deg>64) ~ 0

typedef __attribute__((ext_vector_type(8))) short short8;
typedef __attribute__((ext_vector_type(4))) float f32x4;

__device__ __forceinline__ short f2bf(float f) {
    union { float f; unsigned u; } x; x.f = f;
    unsigned r = x.u + 0x7FFF + ((x.u >> 16) & 1);   // RNE
    return (short)(r >> 16);
}
__device__ __forceinline__ float bf2f(short s) {
    union { unsigned u; float f; } x;
    x.u = ((unsigned)(unsigned short)s) << 16;
    return x.f;
}

// ------------------------------------------------- fp32 -> bf16 convert
__global__ void cvt_bf16(short* __restrict__ dst, const float* __restrict__ src, int n) {
    int i = (blockIdx.x * blockDim.x + threadIdx.x) * 4;
    int stride = gridDim.x * blockDim.x * 4;
    for (; i < n; i += stride) {
        float4 v = *(const float4*)(src + i);
        short4 o;
        o.x = f2bf(v.x); o.y = f2bf(v.y); o.z = f2bf(v.z); o.w = f2bf(v.w);
        *(short4*)(dst + i) = o;
    }
}

// ------------------------------------------------- padded-CSR build: single atomic pass
__global__ void fill_csr_padded(int* __restrict__ csr, int* __restrict__ cnt,
                                const int* __restrict__ srci, const int* __restrict__ dsti, int E) {
    int e = blockIdx.x * blockDim.x + threadIdx.x;
    if (e < E) {
        int d = dsti[e];
        int old = atomicAdd(&cnt[d], 1);
        if (old < CAP) csr[(long)d * CAP + old] = srci[e];
    }
}

// ------------------------------------------------- all weight packs + folded scales, one launch
// blocks 0-7: Wp0, 8-15: Wp1, 16-23: Wp2, 24-27: Wp3, 28: scales
// pack layout (verified R3/R4): Wp[(nt*4+ks)*64+lane][j] = W[ks*32+((lane>>4)&3)*8+j][nt*16+(lane&15)]
// scbuf layout: layer i scale at scbuf+i*256, offset at scbuf+i*256+128
__global__ void prep_all(short* __restrict__ Wp0, short* __restrict__ Wp1,
                         short* __restrict__ Wp2, short* __restrict__ Wp3,
                         const float* __restrict__ W0, const float* __restrict__ W1,
                         const float* __restrict__ W2, const float* __restrict__ W3,
                         float* __restrict__ scbuf,
                         const float* __restrict__ b0, const float* __restrict__ g0,
                         const float* __restrict__ be0, const float* __restrict__ m0,
                         const float* __restrict__ v0,
                         const float* __restrict__ b1, const float* __restrict__ g1,
                         const float* __restrict__ be1, const float* __restrict__ m1,
                         const float* __restrict__ v1,
                         const float* __restrict__ b2, const float* __restrict__ g2,
                         const float* __restrict__ be2, const float* __restrict__ m2,
                         const float* __restrict__ v2,
                         const float* __restrict__ b3) {
    int bid = blockIdx.x;
    if (bid < 24) {
        int layer = bid >> 3;
        int tid = (bid & 7) * 256 + threadIdx.x;       // < 2048 = 8nt*4ks*64lane
        const float* W = layer == 0 ? W0 : layer == 1 ? W1 : W2;
        short* Wp = layer == 0 ? Wp0 : layer == 1 ? Wp1 : Wp2;
        int lane = tid & 63;
        int ks = (tid >> 6) & 3;
        int nt = tid >> 8;
        int n = nt * 16 + (lane & 15);
        int k0 = ks * 32 + ((lane >> 4) & 3) * 8;
        short8 v;
        #pragma unroll
        for (int j = 0; j < 8; j++) v[j] = f2bf(W[(long)(k0 + j) * HDIM + n]);
        ((short8*)Wp)[tid] = v;
    } else if (bid < 28) {
        int tid = (bid - 24) * 256 + threadIdx.x;      // < 1024 = 4nt*4ks*64lane
        int lane = tid & 63;
        int ks = (tid >> 6) & 3;
        int nt = tid >> 8;
        int n = nt * 16 + (lane & 15);
        int k0 = ks * 32 + ((lane >> 4) & 3) * 8;
        short8 v;
        #pragma unroll
        for (int j = 0; j < 8; j++) v[j] = f2bf(W3[(long)(k0 + j) * 64 + n]);
        ((short8*)Wp3)[tid] = v;
    } else {
        // scales: slots 0-127 L0, 128-255 L1, 256-383 L2, 384-447 L3(no BN, 64ch)
        for (int iter = 0; iter < 2; iter++) {
            int slot = iter * 256 + threadIdx.x;
            if (slot < 128) {
                int c = slot;
                float s = g0[c] * rsqrtf(v0[c] + 1e-5f);
                scbuf[c] = s;
                scbuf[128 + c] = (b0[c] - m0[c]) * s + be0[c];
            } else if (slot < 256) {
                int c = slot - 128;
                float s = g1[c] * rsqrtf(v1[c] + 1e-5f);
                scbuf[256 + c] = s;
                scbuf[256 + 128 + c] = (b1[c] - m1[c]) * s + be1[c];
            } else if (slot < 384) {
                int c = slot - 256;
                float s = g2[c] * rsqrtf(v2[c] + 1e-5f);
                scbuf[512 + c] = s;
                scbuf[512 + 128 + c] = (b2[c] - m2[c]) * s + be2[c];
            } else if (slot < 448) {
                int c = slot - 384;
                scbuf[768 + c] = 1.f;
                scbuf[768 + 128 + c] = b3[c];
            }
        }
    }
}

// ------------------------------------------------- fused GIN layer:
//   gather (bf16, padded CSR) -> LDS tile (XOR-swizzled) -> MFMA GEMM + BN + ReLU
//   FINAL=false: write bf16 activations [N][128]
//   FINAL=true : write h to own wave's LDS stripe, second GEMM with Wp2 -> fp32 out [N][64]
template<bool FINAL>
__global__ __launch_bounds__(256) void gin_layer(
        short* __restrict__ outb, float* __restrict__ outf,
        const short* __restrict__ xp,
        const int* __restrict__ cnt, const int* __restrict__ csr,
        const short* __restrict__ Wp,
        const float* __restrict__ scale, const float* __restrict__ offset,
        const short* __restrict__ Wp2,
        const float* __restrict__ scale2, const float* __restrict__ offset2,
        int N) {
    __shared__ short As[64 * HDIM];   // 16 KB, [64 rows][256 B], XOR-swizzled 16B granules
    const int t = threadIdx.x;
    const int row0 = blockIdx.x * 64;

    // ---- Phase A: gather agg = x[i] + sum_j x[j] into LDS (bf16), ILP-4
    const short8* xp8 = (const short8*)xp;   // 16 x 16B chunks per row
    #pragma unroll
    for (int g = 0; g < 4; g++) {
        int rl = g * 16 + (t >> 4);          // local row 0..63
        int chunk = t & 15;
        int node = row0 + rl;
        float facc[8];
        if (node < N) {
            short8 id = xp8[(long)node * 16 + chunk];
            #pragma unroll
            for (int j = 0; j < 8; j++) facc[j] = bf2f(id[j]);
            int deg = cnt[node];
            if (deg > CAP) deg = CAP;
            const int* nb = csr + (long)node * CAP;
            int k = 0;
            for (; k + 4 <= deg; k += 4) {
                int n0 = nb[k], n1 = nb[k + 1], n2 = nb[k + 2], n3 = nb[k + 3];
                short8 v0 = xp8[(long)n0 * 16 + chunk];
                short8 v1 = xp8[(long)n1 * 16 + chunk];
                short8 v2 = xp8[(long)n2 * 16 + chunk];
                short8 v3 = xp8[(long)n3 * 16 + chunk];
                #pragma unroll
                for (int j = 0; j < 8; j++)
                    facc[j] += (bf2f(v0[j]) + bf2f(v1[j])) + (bf2f(v2[j]) + bf2f(v3[j]));
            }
            for (; k < deg; k++) {
                short8 v0 = xp8[(long)nb[k] * 16 + chunk];
                #pragma unroll
                for (int j = 0; j < 8; j++) facc[j] += bf2f(v0[j]);
            }
        } else {
            #pragma unroll
            for (int j = 0; j < 8; j++) facc[j] = 0.f;
        }
        short8 o;
        #pragma unroll
        for (int j = 0; j < 8; j++) o[j] = f2bf(facc[j]);
        int baddr = (rl * 256 + chunk * 16) ^ ((rl & 7) << 4);
        *(short8*)((char*)As + baddr) = o;
    }
    __syncthreads();

    // ---- Phase B: GEMM1 (K=128), A from LDS, B packed from L2
    const int lane = t & 63, w = t >> 6;
    const int rl0 = w * 16 + (lane & 15);    // A-frag row (local)
    const int hi = (lane >> 4) & 3;
    short8 a[4];
    #pragma unroll
    for (int ks = 0; ks < 4; ks++) {
        int baddr = (rl0 * 256 + ks * 64 + hi * 16) ^ ((rl0 & 7) << 4);
        a[ks] = *(const short8*)((const char*)As + baddr);
    }
    const short8* bp = (const short8*)Wp + lane;
    const int c = lane & 15;
    const int rb = hi * 4;                   // C-frag local row base

    #pragma unroll
    for (int nt = 0; nt < 8; nt++) {
        f32x4 acc = {0.f, 0.f, 0.f, 0.f};
        short8 b0 = bp[(nt * 4 + 0) * 64];
        short8 b1 = bp[(nt * 4 + 1) * 64];
        short8 b2 = bp[(nt * 4 + 2) * 64];
        short8 b3 = bp[(nt * 4 + 3) * 64];
        acc = __builtin_amdgcn_mfma_f32_16x16x32_bf16(a[0], b0, acc, 0, 0, 0);
        acc = __builtin_amdgcn_mfma_f32_16x16x32_bf16(a[1], b1, acc, 0, 0, 0);
        acc = __builtin_amdgcn_mfma_f32_16x16x32_bf16(a[2], b2, acc, 0, 0, 0);
        acc = __builtin_amdgcn_mfma_f32_16x16x32_bf16(a[3], b3, acc, 0, 0, 0);
        int cc = nt * 16 + c;
        float s = scale[cc], o = offset[cc];
        if (!FINAL) {
            #pragma unroll
            for (int r = 0; r < 4; r++) {
                int rr = row0 + w * 16 + rb + r;
                if (rr < N) {
                    float val = fmaxf(acc[r] * s + o, 0.f);
                    outb[(long)rr * HDIM + cc] = f2bf(val);
                }
            }
        } else {
            // write h (bf16) back into own wave's LDS stripe (wave-local: no barrier)
            #pragma unroll
            for (int r = 0; r < 4; r++) {
                int rloc = w * 16 + rb + r;
                float val = fmaxf(acc[r] * s + o, 0.f);
                int baddr = (rloc * 256 + cc * 2) ^ ((rloc & 7) << 4);
                *(short*)((char*)As + baddr) = f2bf(val);
            }
        }
    }

    if (FINAL) {
        // ---- GEMM2: out = h @ W3 + b3   (A2 from own stripe, NT2=4)
        short8 a2[4];
        #pragma unroll
        for (int ks = 0; ks < 4; ks++) {
            int baddr = (rl0 * 256 + ks * 64 + hi * 16) ^ ((rl0 & 7) << 4);
            a2[ks] = *(const short8*)((const char*)As + baddr);
        }
        const short8* bp2 = (const short8*)Wp2 + lane;
        #pragma unroll
        for (int nt = 0; nt < 4; nt++) {
            f32x4 acc = {0.f, 0.f, 0.f, 0.f};
            short8 b0 = bp2[(nt * 4 + 0) * 64];
            short8 b1 = bp2[(nt * 4 + 1) * 64];
            short8 b2 = bp2[(nt * 4 + 2) * 64];
            short8 b3v = bp2[(nt * 4 + 3) * 64];
            acc = __builtin_amdgcn_mfma_f32_16x16x32_bf16(a2[0], b0, acc, 0, 0, 0);
            acc = __builtin_amdgcn_mfma_f32_16x16x32_bf16(a2[1], b1, acc, 0, 0, 0);
            acc = __builtin_amdgcn_mfma_f32_16x16x32_bf16(a2[2], b2, acc, 0, 0, 0);
            acc = __builtin_amdgcn_mfma_f32_16x16x32_bf16(a2[3], b3v, acc, 0, 0, 0);
            int cc = nt * 16 + c;
            float s2 = scale2[cc], o2 = offset2[cc];
            #pragma unroll
            for (int r = 0; r < 4; r++) {
                int rr = row0 + w * 16 + rb + r;
                if (rr < N) outf[(long)rr * 64 + cc] = acc[r] * s2 + o2;
            }
        }
    }
}

extern "C" void kernel_launch(void* const* d_in, const int* in_sizes, int n_in,
                              void* d_out, int out_size, void* d_ws, size_t ws_size,
                              hipStream_t stream) {
    const float* x  = (const float*)d_in[0];
    const int*   ei = (const int*)d_in[1];
    const int E = in_sizes[1] / 2;
    const int* srci = ei;
    const int* dsti = ei + E;

    const float* W0 = (const float*)d_in[2];
    const float* b0 = (const float*)d_in[3];
    const float* g0 = (const float*)d_in[4];
    const float* be0 = (const float*)d_in[5];
    const float* m0 = (const float*)d_in[6];
    const float* v0 = (const float*)d_in[7];
    const float* W1 = (const float*)d_in[8];
    const float* b1 = (const float*)d_in[9];
    const float* g1 = (const float*)d_in[10];
    const float* be1 = (const float*)d_in[11];
    const float* m1 = (const float*)d_in[12];
    const float* v1 = (const float*)d_in[13];
    const float* W2 = (const float*)d_in[14];
    const float* b2 = (const float*)d_in[15];
    const float* g2 = (const float*)d_in[16];
    const float* be2 = (const float*)d_in[17];
    const float* m2 = (const float*)d_in[18];
    const float* v2 = (const float*)d_in[19];
    const float* W3 = (const float*)d_in[20];
    const float* b3 = (const float*)d_in[21];

    const int N = in_sizes[0] / HDIM;
    float* out = (float*)d_out;

    // ---- workspace layout (16B-aligned sections)
    short* ba = (short*)d_ws;                        // N*128 bf16
    short* bb = ba + (size_t)N * HDIM;               // N*128 bf16
    int* cnt  = (int*)(bb + (size_t)N * HDIM);       // N (atomic cursors -> degrees)
    int* csr  = cnt + ((N + 3) & ~3);                // N*CAP padded adjacency
    uintptr_t p = ((uintptr_t)(csr + (size_t)N * CAP) + 63) & ~(uintptr_t)63;
    short* Wp0  = (short*)p;                         // 16384 shorts each
    short* Wp1  = Wp0 + 16384;
    short* Wp2  = Wp1 + 16384;
    short* Wp3  = Wp2 + 16384;                       // 8192 shorts
    float* scbuf = (float*)(Wp3 + 8192);             // 4 layers x 256 floats (scale|offset)

    const int edgeBlocks = (E + 255) / 256;
    const int layerBlocks = (N + 63) / 64;
    const int nElem = N * HDIM;
    int cvtBlocks = (nElem / 4 + 255) / 256; if (cvtBlocks > 2048) cvtBlocks = 2048;

    // ---- prep: convert x, build padded CSR (single atomic pass), pack weights+scales
    hipMemsetAsync(cnt, 0, (size_t)N * 4, stream);
    cvt_bf16<<<cvtBlocks, 256, 0, stream>>>(ba, x, nElem);
    fill_csr_padded<<<edgeBlocks, 256, 0, stream>>>(csr, cnt, srci, dsti, E);
    prep_all<<<29, 256, 0, stream>>>(Wp0, Wp1, Wp2, Wp3, W0, W1, W2, W3, scbuf,
                                     b0, g0, be0, m0, v0,
                                     b1, g1, be1, m1, v1,
                                     b2, g2, be2, m2, v2, b3);

    // ---- 3 fused layers (last one also applies W3 -> fp32 out)
    gin_layer<false><<<layerBlocks, 256, 0, stream>>>(
        bb, nullptr, ba, cnt, csr, Wp0, scbuf + 0, scbuf + 128,
        nullptr, nullptr, nullptr, N);
    gin_layer<false><<<layerBlocks, 256, 0, stream>>>(
        ba, nullptr, bb, cnt, csr, Wp1, scbuf + 256, scbuf + 384,
        nullptr, nullptr, nullptr, N);
    gin_layer<true><<<layerBlocks, 256, 0, stream>>>(
        nullptr, out, ba, cnt, csr, Wp2, scbuf + 512, scbuf + 640,
        Wp3, scbuf + 768, scbuf + 896, N);
}

// Round 6
// 179.685 us; speedup vs baseline: 24.0888x; 1.0623x over previous
//
#include <hip/hip_runtime.h>

#define HDIM 128
#define CAP 64   // padded-CSR slots per node; deg ~ Poisson(16), P(deg>64) ~ 0

typedef __attribute__((ext_vector_type(8))) short short8;
typedef __attribute__((ext_vector_type(4))) float f32x4;

__device__ __forceinline__ short f2bf(float f) {
    union { float f; unsigned u; } x; x.f = f;
    unsigned r = x.u + 0x7FFF + ((x.u >> 16) & 1);   // RNE
    return (short)(r >> 16);
}
__device__ __forceinline__ float bf2f(short s) {
    union { unsigned u; float f; } x;
    x.u = ((unsigned)(unsigned short)s) << 16;
    return x.f;
}

// ------------------------------------------------- fp32 -> bf16 convert
__global__ void cvt_bf16(short* __restrict__ dst, const float* __restrict__ src, int n) {
    int i = (blockIdx.x * blockDim.x + threadIdx.x) * 4;
    int stride = gridDim.x * blockDim.x * 4;
    for (; i < n; i += stride) {
        float4 v = *(const float4*)(src + i);
        short4 o;
        o.x = f2bf(v.x); o.y = f2bf(v.y); o.z = f2bf(v.z); o.w = f2bf(v.w);
        *(short4*)(dst + i) = o;
    }
}

// ------------------------------------------------- padded-CSR build: single atomic pass
__global__ void fill_csr_padded(int* __restrict__ csr, int* __restrict__ cnt,
                                const int* __restrict__ srci, const int* __restrict__ dsti, int E) {
    int e = blockIdx.x * blockDim.x + threadIdx.x;
    if (e < E) {
        int d = dsti[e];
        int old = atomicAdd(&cnt[d], 1);
        if (old < CAP) csr[(long)d * CAP + old] = srci[e];
    }
}

// ------------------------------------------------- all weight packs + folded scales, one launch
// blocks 0-7: Wp0, 8-15: Wp1, 16-23: Wp2, 24-27: Wp3, 28: scales
// pack layout (verified R3/R4): Wp[(nt*4+ks)*64+lane][j] = W[ks*32+((lane>>4)&3)*8+j][nt*16+(lane&15)]
// scbuf layout: layer i scale at scbuf+i*256, offset at scbuf+i*256+128
__global__ void prep_all(short* __restrict__ Wp0, short* __restrict__ Wp1,
                         short* __restrict__ Wp2, short* __restrict__ Wp3,
                         const float* __restrict__ W0, const float* __restrict__ W1,
                         const float* __restrict__ W2, const float* __restrict__ W3,
                         float* __restrict__ scbuf,
                         const float* __restrict__ b0, const float* __restrict__ g0,
                         const float* __restrict__ be0, const float* __restrict__ m0,
                         const float* __restrict__ v0,
                         const float* __restrict__ b1, const float* __restrict__ g1,
                         const float* __restrict__ be1, const float* __restrict__ m1,
                         const float* __restrict__ v1,
                         const float* __restrict__ b2, const float* __restrict__ g2,
                         const float* __restrict__ be2, const float* __restrict__ m2,
                         const float* __restrict__ v2,
                         const float* __restrict__ b3) {
    int bid = blockIdx.x;
    if (bid < 24) {
        int layer = bid >> 3;
        int tid = (bid & 7) * 256 + threadIdx.x;       // < 2048 = 8nt*4ks*64lane
        const float* W = layer == 0 ? W0 : layer == 1 ? W1 : W2;
        short* Wp = layer == 0 ? Wp0 : layer == 1 ? Wp1 : Wp2;
        int lane = tid & 63;
        int ks = (tid >> 6) & 3;
        int nt = tid >> 8;
        int n = nt * 16 + (lane & 15);
        int k0 = ks * 32 + ((lane >> 4) & 3) * 8;
        short8 v;
        #pragma unroll
        for (int j = 0; j < 8; j++) v[j] = f2bf(W[(long)(k0 + j) * HDIM + n]);
        ((short8*)Wp)[tid] = v;
    } else if (bid < 28) {
        int tid = (bid - 24) * 256 + threadIdx.x;      // < 1024 = 4nt*4ks*64lane
        int lane = tid & 63;
        int ks = (tid >> 6) & 3;
        int nt = tid >> 8;
        int n = nt * 16 + (lane & 15);
        int k0 = ks * 32 + ((lane >> 4) & 3) * 8;
        short8 v;
        #pragma unroll
        for (int j = 0; j < 8; j++) v[j] = f2bf(W3[(long)(k0 + j) * 64 + n]);
        ((short8*)Wp3)[tid] = v;
    } else {
        // scales: slots 0-127 L0, 128-255 L1, 256-383 L2, 384-447 L3(no BN, 64ch)
        for (int iter = 0; iter < 2; iter++) {
            int slot = iter * 256 + threadIdx.x;
            if (slot < 128) {
                int c = slot;
                float s = g0[c] * rsqrtf(v0[c] + 1e-5f);
                scbuf[c] = s;
                scbuf[128 + c] = (b0[c] - m0[c]) * s + be0[c];
            } else if (slot < 256) {
                int c = slot - 128;
                float s = g1[c] * rsqrtf(v1[c] + 1e-5f);
                scbuf[256 + c] = s;
                scbuf[256 + 128 + c] = (b1[c] - m1[c]) * s + be1[c];
            } else if (slot < 384) {
                int c = slot - 256;
                float s = g2[c] * rsqrtf(v2[c] + 1e-5f);
                scbuf[512 + c] = s;
                scbuf[512 + 128 + c] = (b2[c] - m2[c]) * s + be2[c];
            } else if (slot < 448) {
                int c = slot - 384;
                scbuf[768 + c] = 1.f;
                scbuf[768 + 128 + c] = b3[c];
            }
        }
    }
}

// ------------------------------------------------- fused GIN layer, 16-row tiles:
//   gather (bf16, padded CSR) -> 4KB LDS tile (XOR-swizzled) -> MFMA GEMM + BN + ReLU
//   block = 256 thr = 4 waves; wave w computes col-tiles nt = {2w, 2w+1}
//   FINAL=false: write bf16 activations [N][128]
//   FINAL=true : write h back to LDS (barrier), second GEMM with Wp2 -> fp32 out [N][64]
template<bool FINAL>
__global__ __launch_bounds__(256) void gin_layer(
        short* __restrict__ outb, float* __restrict__ outf,
        const short* __restrict__ xp,
        const int* __restrict__ cnt, const int* __restrict__ csr,
        const short* __restrict__ Wp,
        const float* __restrict__ scale, const float* __restrict__ offset,
        const short* __restrict__ Wp2,
        const float* __restrict__ scale2, const float* __restrict__ offset2,
        int N) {
    __shared__ short As[16 * HDIM];   // 4 KB: [16 rows][256 B], XOR-swizzled 16B granules
    const int t = threadIdx.x;
    const int row0 = blockIdx.x * 16;

    // ---- Phase A: gather agg = x[i] + sum_j x[j] into LDS (bf16), ILP-4
    {
        const short8* xp8 = (const short8*)xp;   // 16 x 16B chunks per row
        int rl = t >> 4;                          // local row 0..15
        int chunk = t & 15;
        int node = row0 + rl;
        float facc[8];
        if (node < N) {
            short8 id = xp8[(long)node * 16 + chunk];
            #pragma unroll
            for (int j = 0; j < 8; j++) facc[j] = bf2f(id[j]);
            int deg = cnt[node];
            if (deg > CAP) deg = CAP;
            const int* nb = csr + (long)node * CAP;
            int k = 0;
            for (; k + 4 <= deg; k += 4) {
                int n0 = nb[k], n1 = nb[k + 1], n2 = nb[k + 2], n3 = nb[k + 3];
                short8 v0 = xp8[(long)n0 * 16 + chunk];
                short8 v1 = xp8[(long)n1 * 16 + chunk];
                short8 v2 = xp8[(long)n2 * 16 + chunk];
                short8 v3 = xp8[(long)n3 * 16 + chunk];
                #pragma unroll
                for (int j = 0; j < 8; j++)
                    facc[j] += (bf2f(v0[j]) + bf2f(v1[j])) + (bf2f(v2[j]) + bf2f(v3[j]));
            }
            for (; k < deg; k++) {
                short8 v0 = xp8[(long)nb[k] * 16 + chunk];
                #pragma unroll
                for (int j = 0; j < 8; j++) facc[j] += bf2f(v0[j]);
            }
        } else {
            #pragma unroll
            for (int j = 0; j < 8; j++) facc[j] = 0.f;
        }
        short8 o;
        #pragma unroll
        for (int j = 0; j < 8; j++) o[j] = f2bf(facc[j]);
        int baddr = (rl * 256 + chunk * 16) ^ ((rl & 7) << 4);
        *(short8*)((char*)As + baddr) = o;
    }
    __syncthreads();

    // ---- Phase B: GEMM1 (K=128), A from LDS (all 16 rows), B packed from L2
    const int lane = t & 63, w = t >> 6;
    const int rl0 = lane & 15;               // A-frag row (local)
    const int hi = (lane >> 4) & 3;
    short8 a[4];
    #pragma unroll
    for (int ks = 0; ks < 4; ks++) {
        int baddr = (rl0 * 256 + ks * 64 + hi * 16) ^ ((rl0 & 7) << 4);
        a[ks] = *(const short8*)((const char*)As + baddr);
    }
    if (FINAL) __syncthreads();              // all a[] loaded before h overwrites As

    const short8* bp = (const short8*)Wp + lane;
    const int c = lane & 15;
    const int rb = hi * 4;                   // C-frag local row base

    #pragma unroll
    for (int i = 0; i < 2; i++) {
        int nt = w * 2 + i;
        f32x4 acc = {0.f, 0.f, 0.f, 0.f};
        short8 b0 = bp[(nt * 4 + 0) * 64];
        short8 b1 = bp[(nt * 4 + 1) * 64];
        short8 b2 = bp[(nt * 4 + 2) * 64];
        short8 b3 = bp[(nt * 4 + 3) * 64];
        acc = __builtin_amdgcn_mfma_f32_16x16x32_bf16(a[0], b0, acc, 0, 0, 0);
        acc = __builtin_amdgcn_mfma_f32_16x16x32_bf16(a[1], b1, acc, 0, 0, 0);
        acc = __builtin_amdgcn_mfma_f32_16x16x32_bf16(a[2], b2, acc, 0, 0, 0);
        acc = __builtin_amdgcn_mfma_f32_16x16x32_bf16(a[3], b3, acc, 0, 0, 0);
        int cc = nt * 16 + c;
        float s = scale[cc], o = offset[cc];
        if (!FINAL) {
            #pragma unroll
            for (int r = 0; r < 4; r++) {
                int rr = row0 + rb + r;
                if (rr < N) {
                    float val = fmaxf(acc[r] * s + o, 0.f);
                    outb[(long)rr * HDIM + cc] = f2bf(val);
                }
            }
        } else {
            // write h (bf16) back into shared LDS tile
            #pragma unroll
            for (int r = 0; r < 4; r++) {
                int rloc = rb + r;
                float val = fmaxf(acc[r] * s + o, 0.f);
                int baddr = (rloc * 256 + cc * 2) ^ ((rloc & 7) << 4);
                *(short*)((char*)As + baddr) = f2bf(val);
            }
        }
    }

    if (FINAL) {
        __syncthreads();                     // h tile complete
        // ---- GEMM2: out = h @ W3 + b3   (wave w -> col-tile w of 64)
        short8 a2[4];
        #pragma unroll
        for (int ks = 0; ks < 4; ks++) {
            int baddr = (rl0 * 256 + ks * 64 + hi * 16) ^ ((rl0 & 7) << 4);
            a2[ks] = *(const short8*)((const char*)As + baddr);
        }
        const short8* bp2 = (const short8*)Wp2 + lane;
        int nt = w;
        f32x4 acc = {0.f, 0.f, 0.f, 0.f};
        short8 b0 = bp2[(nt * 4 + 0) * 64];
        short8 b1 = bp2[(nt * 4 + 1) * 64];
        short8 b2 = bp2[(nt * 4 + 2) * 64];
        short8 b3v = bp2[(nt * 4 + 3) * 64];
        acc = __builtin_amdgcn_mfma_f32_16x16x32_bf16(a2[0], b0, acc, 0, 0, 0);
        acc = __builtin_amdgcn_mfma_f32_16x16x32_bf16(a2[1], b1, acc, 0, 0, 0);
        acc = __builtin_amdgcn_mfma_f32_16x16x32_bf16(a2[2], b2, acc, 0, 0, 0);
        acc = __builtin_amdgcn_mfma_f32_16x16x32_bf16(a2[3], b3v, acc, 0, 0, 0);
        int cc = nt * 16 + c;
        float s2 = scale2[cc], o2 = offset2[cc];
        #pragma unroll
        for (int r = 0; r < 4; r++) {
            int rr = row0 + rb + r;
            if (rr < N) outf[(long)rr * 64 + cc] = acc[r] * s2 + o2;
        }
    }
}

extern "C" void kernel_launch(void* const* d_in, const int* in_sizes, int n_in,
                              void* d_out, int out_size, void* d_ws, size_t ws_size,
                              hipStream_t stream) {
    const float* x  = (const float*)d_in[0];
    const int*   ei = (const int*)d_in[1];
    const int E = in_sizes[1] / 2;
    const int* srci = ei;
    const int* dsti = ei + E;

    const float* W0 = (const float*)d_in[2];
    const float* b0 = (const float*)d_in[3];
    const float* g0 = (const float*)d_in[4];
    const float* be0 = (const float*)d_in[5];
    const float* m0 = (const float*)d_in[6];
    const float* v0 = (const float*)d_in[7];
    const float* W1 = (const float*)d_in[8];
    const float* b1 = (const float*)d_in[9];
    const float* g1 = (const float*)d_in[10];
    const float* be1 = (const float*)d_in[11];
    const float* m1 = (const float*)d_in[12];
    const float* v1 = (const float*)d_in[13];
    const float* W2 = (const float*)d_in[14];
    const float* b2 = (const float*)d_in[15];
    const float* g2 = (const float*)d_in[16];
    const float* be2 = (const float*)d_in[17];
    const float* m2 = (const float*)d_in[18];
    const float* v2 = (const float*)d_in[19];
    const float* W3 = (const float*)d_in[20];
    const float* b3 = (const float*)d_in[21];

    const int N = in_sizes[0] / HDIM;
    float* out = (float*)d_out;

    // ---- workspace layout (16B-aligned sections)
    short* ba = (short*)d_ws;                        // N*128 bf16
    short* bb = ba + (size_t)N * HDIM;               // N*128 bf16
    int* cnt  = (int*)(bb + (size_t)N * HDIM);       // N (atomic cursors -> degrees)
    int* csr  = cnt + ((N + 3) & ~3);                // N*CAP padded adjacency
    uintptr_t p = ((uintptr_t)(csr + (size_t)N * CAP) + 63) & ~(uintptr_t)63;
    short* Wp0  = (short*)p;                         // 16384 shorts each
    short* Wp1  = Wp0 + 16384;
    short* Wp2  = Wp1 + 16384;
    short* Wp3  = Wp2 + 16384;                       // 8192 shorts
    float* scbuf = (float*)(Wp3 + 8192);             // 4 layers x 256 floats (scale|offset)

    const int edgeBlocks = (E + 255) / 256;
    const int layerBlocks = (N + 15) / 16;
    const int nElem = N * HDIM;
    int cvtBlocks = (nElem / 4 + 255) / 256; if (cvtBlocks > 2048) cvtBlocks = 2048;

    // ---- prep: convert x, build padded CSR (single atomic pass), pack weights+scales
    hipMemsetAsync(cnt, 0, (size_t)N * 4, stream);
    cvt_bf16<<<cvtBlocks, 256, 0, stream>>>(ba, x, nElem);
    fill_csr_padded<<<edgeBlocks, 256, 0, stream>>>(csr, cnt, srci, dsti, E);
    prep_all<<<29, 256, 0, stream>>>(Wp0, Wp1, Wp2, Wp3, W0, W1, W2, W3, scbuf,
                                     b0, g0, be0, m0, v0,
                                     b1, g1, be1, m1, v1,
                                     b2, g2, be2, m2, v2, b3);

    // ---- 3 fused layers (last one also applies W3 -> fp32 out)
    gin_layer<false><<<layerBlocks, 256, 0, stream>>>(
        bb, nullptr, ba, cnt, csr, Wp0, scbuf + 0, scbuf + 128,
        nullptr, nullptr, nullptr, N);
    gin_layer<false><<<layerBlocks, 256, 0, stream>>>(
        ba, nullptr, bb, cnt, csr, Wp1, scbuf + 256, scbuf + 384,
        nullptr, nullptr, nullptr, N);
    gin_layer<true><<<layerBlocks, 256, 0, stream>>>(
        nullptr, out, ba, cnt, csr, Wp2, scbuf + 512, scbuf + 640,
        Wp3, scbuf + 768, scbuf + 896, N);
}

// Round 7
// 162.664 us; speedup vs baseline: 26.6095x; 1.1046x over previous
//
#include <hip/hip_runtime.h>

#define HDIM 128
#define NBMAX 512   // max buckets (supports N <= 65536); bucket = dst >> 7

typedef __attribute__((ext_vector_type(8))) short short8;
typedef __attribute__((ext_vector_type(4))) float f32x4;

__device__ __forceinline__ short f2bf(float f) {
    union { float f; unsigned u; } x; x.f = f;
    unsigned r = x.u + 0x7FFF + ((x.u >> 16) & 1);   // RNE
    return (short)(r >> 16);
}
__device__ __forceinline__ float bf2f(short s) {
    union { unsigned u; float f; } x;
    x.u = ((unsigned)(unsigned short)s) << 16;
    return x.f;
}

// ------------------------------------------------- fp32 -> bf16 convert
__global__ void cvt_bf16(short* __restrict__ dst, const float* __restrict__ src, int n) {
    int i = (blockIdx.x * blockDim.x + threadIdx.x) * 4;
    int stride = gridDim.x * blockDim.x * 4;
    for (; i < n; i += stride) {
        float4 v = *(const float4*)(src + i);
        short4 o;
        o.x = f2bf(v.x); o.y = f2bf(v.y); o.z = f2bf(v.z); o.w = f2bf(v.w);
        *(short4*)(dst + i) = o;
    }
}

// ------------------------------------------------- pass 1: bucket histogram
__global__ void hist_buckets(int* __restrict__ ghist, const int* __restrict__ dsti, int E, int NB) {
    __shared__ int h[NBMAX];
    for (int b = threadIdx.x; b < NBMAX; b += 256) h[b] = 0;
    __syncthreads();
    int e = blockIdx.x * blockDim.x + threadIdx.x;
    int stride = gridDim.x * blockDim.x;
    for (; e < E; e += stride) atomicAdd(&h[dsti[e] >> 7], 1);
    __syncthreads();
    for (int b = threadIdx.x; b < NB; b += 256) { int c = h[b]; if (c) atomicAdd(&ghist[b], c); }
}

// ------------------------------------------------- pass 2: 1-wave bucket scan
__global__ void scan_buckets(int* __restrict__ bucketPtr, int* __restrict__ bucketCur,
                             const int* __restrict__ ghist, int NB,
                             int* __restrict__ rowptr, int N, int E) {
    int lane = threadIdx.x;   // 64 threads
    int carry = 0;
    int nch = (NB + 63) / 64;
    for (int s = 0; s < nch; s++) {
        int idx = s * 64 + lane;
        int c = idx < NB ? ghist[idx] : 0;
        int inc = c;
        #pragma unroll
        for (int st = 1; st < 64; st <<= 1) { int n = __shfl_up(inc, st, 64); if (lane >= st) inc += n; }
        int exc = inc - c + carry;
        if (idx < NB) { bucketPtr[idx] = exc; bucketCur[idx] = exc; }
        carry += __shfl(inc, 63, 64);
    }
    if (lane == 0) { bucketPtr[NB] = carry; rowptr[N] = E; }
}

// ------------------------------------------------- pass 3: scatter records bucket-major
// record = (dstLocal << 16) | src  (src < 65536)
__global__ __launch_bounds__(256) void scatter_recs(int* __restrict__ recs, int* __restrict__ bucketCur,
                                                    const int* __restrict__ srci, const int* __restrict__ dsti,
                                                    int E, int NB) {
    __shared__ int hist[NBMAX];
    __shared__ int gb[NBMAX];
    const int t = threadIdx.x;
    const int base = blockIdx.x * 4096;
    for (int b = t; b < NBMAX; b += 256) hist[b] = 0;
    __syncthreads();
    #pragma unroll
    for (int i = 0; i < 16; i++) {
        int e = base + i * 256 + t;
        if (e < E) atomicAdd(&hist[dsti[e] >> 7], 1);
    }
    __syncthreads();
    for (int b = t; b < NB; b += 256) {
        int c = hist[b];
        gb[b] = c ? atomicAdd(&bucketCur[b], c) : 0;
        hist[b] = 0;                                   // reuse as local cursor
    }
    __syncthreads();
    #pragma unroll
    for (int i = 0; i < 16; i++) {
        int e = base + i * 256 + t;
        if (e < E) {
            int d = dsti[e], s = srci[e];
            int b = d >> 7;
            int off = atomicAdd(&hist[b], 1);
            recs[gb[b] + off] = ((d & 127) << 16) | s;
        }
    }
}

// ------------------------------------------------- pass 4: per-bucket local CSR build
// writes rowptr (true CSR) + node-sorted u16 src list (block-owned region -> full-line writes)
__global__ __launch_bounds__(256) void build_csr_local(
        unsigned short* __restrict__ csrH, int* __restrict__ rowptr,
        const int* __restrict__ recs, const int* __restrict__ bucketPtr, int N) {
    const int b = blockIdx.x;
    const int base = bucketPtr[b];
    const int cnt  = bucketPtr[b + 1] - base;
    __shared__ int nh[128];
    __shared__ int cur[128];
    const int t = threadIdx.x;
    if (t < 128) nh[t] = 0;
    __syncthreads();
    for (int i = t; i < cnt; i += 256) atomicAdd(&nh[recs[base + i] >> 16], 1);
    __syncthreads();
    if (t < 64) {
        int lane = t;
        int c0 = nh[lane], c1 = nh[64 + lane];
        int i0 = c0;
        #pragma unroll
        for (int s = 1; s < 64; s <<= 1) { int n = __shfl_up(i0, s, 64); if (lane >= s) i0 += n; }
        int tot0 = __shfl(i0, 63, 64);
        int i1 = c1;
        #pragma unroll
        for (int s = 1; s < 64; s <<= 1) { int n = __shfl_up(i1, s, 64); if (lane >= s) i1 += n; }
        i1 += tot0;
        int e0 = i0 - c0, e1 = i1 - c1;
        cur[lane] = e0; cur[64 + lane] = e1;
        int idx0 = b * 128 + lane, idx1 = b * 128 + 64 + lane;
        if (idx0 <= N) rowptr[idx0] = base + e0;
        if (idx1 <= N) rowptr[idx1] = base + e1;
    }
    __syncthreads();
    for (int i = t; i < cnt; i += 256) {
        int r = recs[base + i];
        int off = atomicAdd(&cur[r >> 16], 1);
        csrH[base + off] = (unsigned short)(r & 0xffff);
    }
}

// ------------------------------------------------- all weight packs + folded scales, one launch
// blocks 0-7: Wp0, 8-15: Wp1, 16-23: Wp2, 24-27: Wp3, 28: scales
// pack layout (verified R3-R6): Wp[(nt*4+ks)*64+lane][j] = W[ks*32+((lane>>4)&3)*8+j][nt*16+(lane&15)]
__global__ void prep_all(short* __restrict__ Wp0, short* __restrict__ Wp1,
                         short* __restrict__ Wp2, short* __restrict__ Wp3,
                         const float* __restrict__ W0, const float* __restrict__ W1,
                         const float* __restrict__ W2, const float* __restrict__ W3,
                         float* __restrict__ scbuf,
                         const float* __restrict__ b0, const float* __restrict__ g0,
                         const float* __restrict__ be0, const float* __restrict__ m0,
                         const float* __restrict__ v0,
                         const float* __restrict__ b1, const float* __restrict__ g1,
                         const float* __restrict__ be1, const float* __restrict__ m1,
                         const float* __restrict__ v1,
                         const float* __restrict__ b2, const float* __restrict__ g2,
                         const float* __restrict__ be2, const float* __restrict__ m2,
                         const float* __restrict__ v2,
                         const float* __restrict__ b3) {
    int bid = blockIdx.x;
    if (bid < 24) {
        int layer = bid >> 3;
        int tid = (bid & 7) * 256 + threadIdx.x;
        const float* W = layer == 0 ? W0 : layer == 1 ? W1 : W2;
        short* Wp = layer == 0 ? Wp0 : layer == 1 ? Wp1 : Wp2;
        int lane = tid & 63;
        int ks = (tid >> 6) & 3;
        int nt = tid >> 8;
        int n = nt * 16 + (lane & 15);
        int k0 = ks * 32 + ((lane >> 4) & 3) * 8;
        short8 v;
        #pragma unroll
        for (int j = 0; j < 8; j++) v[j] = f2bf(W[(long)(k0 + j) * HDIM + n]);
        ((short8*)Wp)[tid] = v;
    } else if (bid < 28) {
        int tid = (bid - 24) * 256 + threadIdx.x;
        int lane = tid & 63;
        int ks = (tid >> 6) & 3;
        int nt = tid >> 8;
        int n = nt * 16 + (lane & 15);
        int k0 = ks * 32 + ((lane >> 4) & 3) * 8;
        short8 v;
        #pragma unroll
        for (int j = 0; j < 8; j++) v[j] = f2bf(W3[(long)(k0 + j) * 64 + n]);
        ((short8*)Wp3)[tid] = v;
    } else {
        for (int iter = 0; iter < 2; iter++) {
            int slot = iter * 256 + threadIdx.x;
            if (slot < 128) {
                int c = slot;
                float s = g0[c] * rsqrtf(v0[c] + 1e-5f);
                scbuf[c] = s;
                scbuf[128 + c] = (b0[c] - m0[c]) * s + be0[c];
            } else if (slot < 256) {
                int c = slot - 128;
                float s = g1[c] * rsqrtf(v1[c] + 1e-5f);
                scbuf[256 + c] = s;
                scbuf[256 + 128 + c] = (b1[c] - m1[c]) * s + be1[c];
            } else if (slot < 384) {
                int c = slot - 256;
                float s = g2[c] * rsqrtf(v2[c] + 1e-5f);
                scbuf[512 + c] = s;
                scbuf[512 + 128 + c] = (b2[c] - m2[c]) * s + be2[c];
            } else if (slot < 448) {
                int c = slot - 384;
                scbuf[768 + c] = 1.f;
                scbuf[768 + 128 + c] = b3[c];
            }
        }
    }
}

// ------------------------------------------------- fused GIN layer, 16-row tiles:
//   gather (bf16, CSR u16) -> 4KB LDS tile (XOR-swizzled) -> MFMA GEMM + BN + ReLU
//   block = 256 thr = 4 waves; wave w computes col-tiles nt = {2w, 2w+1}
//   FINAL=false: write bf16 activations [N][128]
//   FINAL=true : write h back to LDS (barrier), second GEMM with Wp2 -> fp32 out [N][64]
template<bool FINAL>
__global__ __launch_bounds__(256) void gin_layer(
        short* __restrict__ outb, float* __restrict__ outf,
        const short* __restrict__ xp,
        const int* __restrict__ rowptr, const unsigned short* __restrict__ csrH,
        const short* __restrict__ Wp,
        const float* __restrict__ scale, const float* __restrict__ offset,
        const short* __restrict__ Wp2,
        const float* __restrict__ scale2, const float* __restrict__ offset2,
        int N) {
    __shared__ short As[16 * HDIM];   // 4 KB: [16 rows][256 B], XOR-swizzled 16B granules
    const int t = threadIdx.x;
    const int row0 = blockIdx.x * 16;

    // ---- Phase A: gather agg = x[i] + sum_j x[j] into LDS (bf16), ILP-4
    {
        const short8* xp8 = (const short8*)xp;   // 16 x 16B chunks per row
        int rl = t >> 4;                          // local row 0..15
        int chunk = t & 15;
        int node = row0 + rl;
        float facc[8];
        if (node < N) {
            short8 id = xp8[(long)node * 16 + chunk];
            #pragma unroll
            for (int j = 0; j < 8; j++) facc[j] = bf2f(id[j]);
            int s0 = rowptr[node], s1 = rowptr[node + 1];
            int deg = s1 - s0;
            const unsigned short* nb = csrH + s0;
            int k = 0;
            for (; k + 4 <= deg; k += 4) {
                int n0 = nb[k], n1 = nb[k + 1], n2 = nb[k + 2], n3 = nb[k + 3];
                short8 v0 = xp8[(long)n0 * 16 + chunk];
                short8 v1 = xp8[(long)n1 * 16 + chunk];
                short8 v2 = xp8[(long)n2 * 16 + chunk];
                short8 v3 = xp8[(long)n3 * 16 + chunk];
                #pragma unroll
                for (int j = 0; j < 8; j++)
                    facc[j] += (bf2f(v0[j]) + bf2f(v1[j])) + (bf2f(v2[j]) + bf2f(v3[j]));
            }
            for (; k < deg; k++) {
                short8 v0 = xp8[(long)nb[k] * 16 + chunk];
                #pragma unroll
                for (int j = 0; j < 8; j++) facc[j] += bf2f(v0[j]);
            }
        } else {
            #pragma unroll
            for (int j = 0; j < 8; j++) facc[j] = 0.f;
        }
        short8 o;
        #pragma unroll
        for (int j = 0; j < 8; j++) o[j] = f2bf(facc[j]);
        int baddr = (rl * 256 + chunk * 16) ^ ((rl & 7) << 4);
        *(short8*)((char*)As + baddr) = o;
    }
    __syncthreads();

    // ---- Phase B: GEMM1 (K=128), A from LDS (all 16 rows), B packed from L2
    const int lane = t & 63, w = t >> 6;
    const int rl0 = lane & 15;               // A-frag row (local)
    const int hi = (lane >> 4) & 3;
    short8 a[4];
    #pragma unroll
    for (int ks = 0; ks < 4; ks++) {
        int baddr = (rl0 * 256 + ks * 64 + hi * 16) ^ ((rl0 & 7) << 4);
        a[ks] = *(const short8*)((const char*)As + baddr);
    }
    if (FINAL) __syncthreads();              // all a[] loaded before h overwrites As

    const short8* bp = (const short8*)Wp + lane;
    const int c = lane & 15;
    const int rb = hi * 4;                   // C-frag local row base

    #pragma unroll
    for (int i = 0; i < 2; i++) {
        int nt = w * 2 + i;
        f32x4 acc = {0.f, 0.f, 0.f, 0.f};
        short8 b0 = bp[(nt * 4 + 0) * 64];
        short8 b1 = bp[(nt * 4 + 1) * 64];
        short8 b2 = bp[(nt * 4 + 2) * 64];
        short8 b3 = bp[(nt * 4 + 3) * 64];
        acc = __builtin_amdgcn_mfma_f32_16x16x32_bf16(a[0], b0, acc, 0, 0, 0);
        acc = __builtin_amdgcn_mfma_f32_16x16x32_bf16(a[1], b1, acc, 0, 0, 0);
        acc = __builtin_amdgcn_mfma_f32_16x16x32_bf16(a[2], b2, acc, 0, 0, 0);
        acc = __builtin_amdgcn_mfma_f32_16x16x32_bf16(a[3], b3, acc, 0, 0, 0);
        int cc = nt * 16 + c;
        float s = scale[cc], o = offset[cc];
        if (!FINAL) {
            #pragma unroll
            for (int r = 0; r < 4; r++) {
                int rr = row0 + rb + r;
                if (rr < N) {
                    float val = fmaxf(acc[r] * s + o, 0.f);
                    outb[(long)rr * HDIM + cc] = f2bf(val);
                }
            }
        } else {
            #pragma unroll
            for (int r = 0; r < 4; r++) {
                int rloc = rb + r;
                float val = fmaxf(acc[r] * s + o, 0.f);
                int baddr = (rloc * 256 + cc * 2) ^ ((rloc & 7) << 4);
                *(short*)((char*)As + baddr) = f2bf(val);
            }
        }
    }

    if (FINAL) {
        __syncthreads();                     // h tile complete
        short8 a2[4];
        #pragma unroll
        for (int ks = 0; ks < 4; ks++) {
            int baddr = (rl0 * 256 + ks * 64 + hi * 16) ^ ((rl0 & 7) << 4);
            a2[ks] = *(const short8*)((const char*)As + baddr);
        }
        const short8* bp2 = (const short8*)Wp2 + lane;
        int nt = w;
        f32x4 acc = {0.f, 0.f, 0.f, 0.f};
        short8 b0 = bp2[(nt * 4 + 0) * 64];
        short8 b1 = bp2[(nt * 4 + 1) * 64];
        short8 b2 = bp2[(nt * 4 + 2) * 64];
        short8 b3v = bp2[(nt * 4 + 3) * 64];
        acc = __builtin_amdgcn_mfma_f32_16x16x32_bf16(a2[0], b0, acc, 0, 0, 0);
        acc = __builtin_amdgcn_mfma_f32_16x16x32_bf16(a2[1], b1, acc, 0, 0, 0);
        acc = __builtin_amdgcn_mfma_f32_16x16x32_bf16(a2[2], b2, acc, 0, 0, 0);
        acc = __builtin_amdgcn_mfma_f32_16x16x32_bf16(a2[3], b3v, acc, 0, 0, 0);
        int cc = nt * 16 + c;
        float s2 = scale2[cc], o2 = offset2[cc];
        #pragma unroll
        for (int r = 0; r < 4; r++) {
            int rr = row0 + rb + r;
            if (rr < N) outf[(long)rr * 64 + cc] = acc[r] * s2 + o2;
        }
    }
}

extern "C" void kernel_launch(void* const* d_in, const int* in_sizes, int n_in,
                              void* d_out, int out_size, void* d_ws, size_t ws_size,
                              hipStream_t stream) {
    const float* x  = (const float*)d_in[0];
    const int*   ei = (const int*)d_in[1];
    const int E = in_sizes[1] / 2;
    const int* srci = ei;
    const int* dsti = ei + E;

    const float* W0 = (const float*)d_in[2];
    const float* b0 = (const float*)d_in[3];
    const float* g0 = (const float*)d_in[4];
    const float* be0 = (const float*)d_in[5];
    const float* m0 = (const float*)d_in[6];
    const float* v0 = (const float*)d_in[7];
    const float* W1 = (const float*)d_in[8];
    const float* b1 = (const float*)d_in[9];
    const float* g1 = (const float*)d_in[10];
    const float* be1 = (const float*)d_in[11];
    const float* m1 = (const float*)d_in[12];
    const float* v1 = (const float*)d_in[13];
    const float* W2 = (const float*)d_in[14];
    const float* b2 = (const float*)d_in[15];
    const float* g2 = (const float*)d_in[16];
    const float* be2 = (const float*)d_in[17];
    const float* m2 = (const float*)d_in[18];
    const float* v2 = (const float*)d_in[19];
    const float* W3 = (const float*)d_in[20];
    const float* b3 = (const float*)d_in[21];

    const int N = in_sizes[0] / HDIM;
    const int NB = (N + 127) >> 7;                   // buckets of 128 nodes
    float* out = (float*)d_out;

    // ---- workspace layout (16B-aligned sections)
    short* ba = (short*)d_ws;                        // N*128 bf16
    short* bb = ba + (size_t)N * HDIM;               // N*128 bf16
    int* rowptr = (int*)(bb + (size_t)N * HDIM);     // N+1
    int* recs   = rowptr + ((N + 2 + 3) & ~3);       // E records (dstLocal<<16|src)
    unsigned short* csrH = (unsigned short*)(recs + E);  // E u16 srcs
    int* ghist = (int*)(((uintptr_t)(csrH + E) + 63) & ~(uintptr_t)63);  // NBMAX
    int* bucketPtr = ghist + NBMAX;                  // NB+1
    int* bucketCur = bucketPtr + NBMAX + 4;          // NB
    short* Wp0 = (short*)(((uintptr_t)(bucketCur + NBMAX) + 63) & ~(uintptr_t)63);
    short* Wp1  = Wp0 + 16384;
    short* Wp2  = Wp1 + 16384;
    short* Wp3  = Wp2 + 16384;                       // 8192 shorts
    float* scbuf = (float*)(Wp3 + 8192);             // 4 layers x 256 floats (scale|offset)

    const int layerBlocks = (N + 15) / 16;
    const int nElem = N * HDIM;
    int cvtBlocks = (nElem / 4 + 255) / 256; if (cvtBlocks > 2048) cvtBlocks = 2048;

    // ---- prep: convert x, radix CSR build, pack weights+scales
    hipMemsetAsync(ghist, 0, NBMAX * 4, stream);
    cvt_bf16<<<cvtBlocks, 256, 0, stream>>>(ba, x, nElem);
    hist_buckets<<<256, 256, 0, stream>>>(ghist, dsti, E, NB);
    scan_buckets<<<1, 64, 0, stream>>>(bucketPtr, bucketCur, ghist, NB, rowptr, N, E);
    scatter_recs<<<(E + 4095) / 4096, 256, 0, stream>>>(recs, bucketCur, srci, dsti, E, NB);
    build_csr_local<<<NB, 256, 0, stream>>>(csrH, rowptr, recs, bucketPtr, N);
    prep_all<<<29, 256, 0, stream>>>(Wp0, Wp1, Wp2, Wp3, W0, W1, W2, W3, scbuf,
                                     b0, g0, be0, m0, v0,
                                     b1, g1, be1, m1, v1,
                                     b2, g2, be2, m2, v2, b3);

    // ---- 3 fused layers (last one also applies W3 -> fp32 out)
    gin_layer<false><<<layerBlocks, 256, 0, stream>>>(
        bb, nullptr, ba, rowptr, csrH, Wp0, scbuf + 0, scbuf + 128,
        nullptr, nullptr, nullptr, N);
    gin_layer<false><<<layerBlocks, 256, 0, stream>>>(
        ba, nullptr, bb, rowptr, csrH, Wp1, scbuf + 256, scbuf + 384,
        nullptr, nullptr, nullptr, N);
    gin_layer<true><<<layerBlocks, 256, 0, stream>>>(
        nullptr, out, ba, rowptr, csrH, Wp2, scbuf + 512, scbuf + 640,
        Wp3, scbuf + 768, scbuf + 896, N);
}

// Round 8
// 160.258 us; speedup vs baseline: 27.0090x; 1.0150x over previous
//
#include <hip/hip_runtime.h>

#define HDIM 128
#define NBMAX 512   // max buckets (supports N <= 65536); bucket = dst >> 7

typedef __attribute__((ext_vector_type(8))) short short8;
typedef __attribute__((ext_vector_type(4))) float f32x4;

__device__ __forceinline__ short f2bf(float f) {
    union { float f; unsigned u; } x; x.f = f;
    unsigned r = x.u + 0x7FFF + ((x.u >> 16) & 1);   // RNE
    return (short)(r >> 16);
}
__device__ __forceinline__ float bf2f(short s) {
    union { unsigned u; float f; } x;
    x.u = ((unsigned)(unsigned short)s) << 16;
    return x.f;
}

// ------------------------------------------------- fp32 -> bf16 convert
__global__ void cvt_bf16(short* __restrict__ dst, const float* __restrict__ src, int n) {
    int i = (blockIdx.x * blockDim.x + threadIdx.x) * 4;
    int stride = gridDim.x * blockDim.x * 4;
    for (; i < n; i += stride) {
        float4 v = *(const float4*)(src + i);
        short4 o;
        o.x = f2bf(v.x); o.y = f2bf(v.y); o.z = f2bf(v.z); o.w = f2bf(v.w);
        *(short4*)(dst + i) = o;
    }
}

// ------------------------------------------------- pass 1: bucket histogram
__global__ void hist_buckets(int* __restrict__ ghist, const int* __restrict__ dsti, int E, int NB) {
    __shared__ int h[NBMAX];
    for (int b = threadIdx.x; b < NBMAX; b += 256) h[b] = 0;
    __syncthreads();
    int e = blockIdx.x * blockDim.x + threadIdx.x;
    int stride = gridDim.x * blockDim.x;
    for (; e < E; e += stride) atomicAdd(&h[dsti[e] >> 7], 1);
    __syncthreads();
    for (int b = threadIdx.x; b < NB; b += 256) { int c = h[b]; if (c) atomicAdd(&ghist[b], c); }
}

// ------------------------------------------------- pass 2: 1-wave bucket scan
__global__ void scan_buckets(int* __restrict__ bucketPtr, int* __restrict__ bucketCur,
                             const int* __restrict__ ghist, int NB,
                             int* __restrict__ rowptr, int N, int E) {
    int lane = threadIdx.x;   // 64 threads
    int carry = 0;
    int nch = (NB + 63) / 64;
    for (int s = 0; s < nch; s++) {
        int idx = s * 64 + lane;
        int c = idx < NB ? ghist[idx] : 0;
        int inc = c;
        #pragma unroll
        for (int st = 1; st < 64; st <<= 1) { int n = __shfl_up(inc, st, 64); if (lane >= st) inc += n; }
        int exc = inc - c + carry;
        if (idx < NB) { bucketPtr[idx] = exc; bucketCur[idx] = exc; }
        carry += __shfl(inc, 63, 64);
    }
    if (lane == 0) { bucketPtr[NB] = carry; rowptr[N] = E; }
}

// ------------------------------------------------- pass 3: scatter records bucket-major
// record = (dstLocal << 16) | src  (src < 65536)
__global__ __launch_bounds__(256) void scatter_recs(int* __restrict__ recs, int* __restrict__ bucketCur,
                                                    const int* __restrict__ srci, const int* __restrict__ dsti,
                                                    int E, int NB) {
    __shared__ int hist[NBMAX];
    __shared__ int gb[NBMAX];
    const int t = threadIdx.x;
    const int base = blockIdx.x * 4096;
    for (int b = t; b < NBMAX; b += 256) hist[b] = 0;
    __syncthreads();
    #pragma unroll
    for (int i = 0; i < 16; i++) {
        int e = base + i * 256 + t;
        if (e < E) atomicAdd(&hist[dsti[e] >> 7], 1);
    }
    __syncthreads();
    for (int b = t; b < NB; b += 256) {
        int c = hist[b];
        gb[b] = c ? atomicAdd(&bucketCur[b], c) : 0;
        hist[b] = 0;                                   // reuse as local cursor
    }
    __syncthreads();
    #pragma unroll
    for (int i = 0; i < 16; i++) {
        int e = base + i * 256 + t;
        if (e < E) {
            int d = dsti[e], s = srci[e];
            int b = d >> 7;
            int off = atomicAdd(&hist[b], 1);
            recs[gb[b] + off] = ((d & 127) << 16) | s;
        }
    }
}

// ------------------------------------------------- pass 4: per-bucket local CSR build
__global__ __launch_bounds__(256) void build_csr_local(
        unsigned short* __restrict__ csrH, int* __restrict__ rowptr,
        const int* __restrict__ recs, const int* __restrict__ bucketPtr, int N) {
    const int b = blockIdx.x;
    const int base = bucketPtr[b];
    const int cnt  = bucketPtr[b + 1] - base;
    __shared__ int nh[128];
    __shared__ int cur[128];
    const int t = threadIdx.x;
    if (t < 128) nh[t] = 0;
    __syncthreads();
    for (int i = t; i < cnt; i += 256) atomicAdd(&nh[recs[base + i] >> 16], 1);
    __syncthreads();
    if (t < 64) {
        int lane = t;
        int c0 = nh[lane], c1 = nh[64 + lane];
        int i0 = c0;
        #pragma unroll
        for (int s = 1; s < 64; s <<= 1) { int n = __shfl_up(i0, s, 64); if (lane >= s) i0 += n; }
        int tot0 = __shfl(i0, 63, 64);
        int i1 = c1;
        #pragma unroll
        for (int s = 1; s < 64; s <<= 1) { int n = __shfl_up(i1, s, 64); if (lane >= s) i1 += n; }
        i1 += tot0;
        int e0 = i0 - c0, e1 = i1 - c1;
        cur[lane] = e0; cur[64 + lane] = e1;
        int idx0 = b * 128 + lane, idx1 = b * 128 + 64 + lane;
        if (idx0 <= N) rowptr[idx0] = base + e0;
        if (idx1 <= N) rowptr[idx1] = base + e1;
    }
    __syncthreads();
    for (int i = t; i < cnt; i += 256) {
        int r = recs[base + i];
        int off = atomicAdd(&cur[r >> 16], 1);
        csrH[base + off] = (unsigned short)(r & 0xffff);
    }
}

// ------------------------------------------------- all weight packs + folded scales + ghist zero
// blocks 0-7: Wp0, 8-15: Wp1, 16-23: Wp2, 24-27: Wp3, 28: scales, 29: zero ghist
// pack layout (verified R3-R7): Wp[(nt*4+ks)*64+lane][j] = W[ks*32+((lane>>4)&3)*8+j][nt*16+(lane&15)]
__global__ void prep_all(short* __restrict__ Wp0, short* __restrict__ Wp1,
                         short* __restrict__ Wp2, short* __restrict__ Wp3,
                         const float* __restrict__ W0, const float* __restrict__ W1,
                         const float* __restrict__ W2, const float* __restrict__ W3,
                         float* __restrict__ scbuf, int* __restrict__ ghist,
                         const float* __restrict__ b0, const float* __restrict__ g0,
                         const float* __restrict__ be0, const float* __restrict__ m0,
                         const float* __restrict__ v0,
                         const float* __restrict__ b1, const float* __restrict__ g1,
                         const float* __restrict__ be1, const float* __restrict__ m1,
                         const float* __restrict__ v1,
                         const float* __restrict__ b2, const float* __restrict__ g2,
                         const float* __restrict__ be2, const float* __restrict__ m2,
                         const float* __restrict__ v2,
                         const float* __restrict__ b3) {
    int bid = blockIdx.x;
    if (bid < 24) {
        int layer = bid >> 3;
        int tid = (bid & 7) * 256 + threadIdx.x;
        const float* W = layer == 0 ? W0 : layer == 1 ? W1 : W2;
        short* Wp = layer == 0 ? Wp0 : layer == 1 ? Wp1 : Wp2;
        int lane = tid & 63;
        int ks = (tid >> 6) & 3;
        int nt = tid >> 8;
        int n = nt * 16 + (lane & 15);
        int k0 = ks * 32 + ((lane >> 4) & 3) * 8;
        short8 v;
        #pragma unroll
        for (int j = 0; j < 8; j++) v[j] = f2bf(W[(long)(k0 + j) * HDIM + n]);
        ((short8*)Wp)[tid] = v;
    } else if (bid < 28) {
        int tid = (bid - 24) * 256 + threadIdx.x;
        int lane = tid & 63;
        int ks = (tid >> 6) & 3;
        int nt = tid >> 8;
        int n = nt * 16 + (lane & 15);
        int k0 = ks * 32 + ((lane >> 4) & 3) * 8;
        short8 v;
        #pragma unroll
        for (int j = 0; j < 8; j++) v[j] = f2bf(W3[(long)(k0 + j) * 64 + n]);
        ((short8*)Wp3)[tid] = v;
    } else if (bid == 28) {
        for (int iter = 0; iter < 2; iter++) {
            int slot = iter * 256 + threadIdx.x;
            if (slot < 128) {
                int c = slot;
                float s = g0[c] * rsqrtf(v0[c] + 1e-5f);
                scbuf[c] = s;
                scbuf[128 + c] = (b0[c] - m0[c]) * s + be0[c];
            } else if (slot < 256) {
                int c = slot - 128;
                float s = g1[c] * rsqrtf(v1[c] + 1e-5f);
                scbuf[256 + c] = s;
                scbuf[256 + 128 + c] = (b1[c] - m1[c]) * s + be1[c];
            } else if (slot < 384) {
                int c = slot - 256;
                float s = g2[c] * rsqrtf(v2[c] + 1e-5f);
                scbuf[512 + c] = s;
                scbuf[512 + 128 + c] = (b2[c] - m2[c]) * s + be2[c];
            } else if (slot < 448) {
                int c = slot - 384;
                scbuf[768 + c] = 1.f;
                scbuf[768 + 128 + c] = b3[c];
            }
        }
    } else {
        // zero ghist (replaces hipMemsetAsync -> rocclr fillBuffer, 42us in-graph!)
        ghist[threadIdx.x] = 0;
        ghist[256 + threadIdx.x] = 0;
    }
}

// ------------------------------------------------- fused GIN layer, 16-row tiles:
//   gather (bf16, CSR u16) -> 4KB LDS tile (XOR-swizzled) -> MFMA GEMM + BN + ReLU
//   block = 256 thr = 4 waves; wave w computes col-tiles nt = {2w, 2w+1}
//   FINAL=false: write bf16 activations [N][128]
//   FINAL=true : write h back to LDS (barrier), second GEMM with Wp2 -> fp32 out [N][64]
template<bool FINAL>
__global__ __launch_bounds__(256) void gin_layer(
        short* __restrict__ outb, float* __restrict__ outf,
        const short* __restrict__ xp,
        const int* __restrict__ rowptr, const unsigned short* __restrict__ csrH,
        const short* __restrict__ Wp,
        const float* __restrict__ scale, const float* __restrict__ offset,
        const short* __restrict__ Wp2,
        const float* __restrict__ scale2, const float* __restrict__ offset2,
        int N) {
    __shared__ short As[16 * HDIM];   // 4 KB: [16 rows][256 B], XOR-swizzled 16B granules
    const int t = threadIdx.x;
    const int row0 = blockIdx.x * 16;

    // ---- Phase A: gather agg = x[i] + sum_j x[j] into LDS (bf16), ILP-4
    {
        const short8* xp8 = (const short8*)xp;   // 16 x 16B chunks per row
        int rl = t >> 4;                          // local row 0..15
        int chunk = t & 15;
        int node = row0 + rl;
        float facc[8];
        if (node < N) {
            short8 id = xp8[(long)node * 16 + chunk];
            #pragma unroll
            for (int j = 0; j < 8; j++) facc[j] = bf2f(id[j]);
            int s0 = rowptr[node], s1 = rowptr[node + 1];
            int deg = s1 - s0;
            const unsigned short* nb = csrH + s0;
            int k = 0;
            for (; k + 4 <= deg; k += 4) {
                int n0 = nb[k], n1 = nb[k + 1], n2 = nb[k + 2], n3 = nb[k + 3];
                short8 v0 = xp8[(long)n0 * 16 + chunk];
                short8 v1 = xp8[(long)n1 * 16 + chunk];
                short8 v2 = xp8[(long)n2 * 16 + chunk];
                short8 v3 = xp8[(long)n3 * 16 + chunk];
                #pragma unroll
                for (int j = 0; j < 8; j++)
                    facc[j] += (bf2f(v0[j]) + bf2f(v1[j])) + (bf2f(v2[j]) + bf2f(v3[j]));
            }
            for (; k < deg; k++) {
                short8 v0 = xp8[(long)nb[k] * 16 + chunk];
                #pragma unroll
                for (int j = 0; j < 8; j++) facc[j] += bf2f(v0[j]);
            }
        } else {
            #pragma unroll
            for (int j = 0; j < 8; j++) facc[j] = 0.f;
        }
        short8 o;
        #pragma unroll
        for (int j = 0; j < 8; j++) o[j] = f2bf(facc[j]);
        int baddr = (rl * 256 + chunk * 16) ^ ((rl & 7) << 4);
        *(short8*)((char*)As + baddr) = o;
    }
    __syncthreads();

    // ---- Phase B: GEMM1 (K=128), A from LDS (all 16 rows), B packed from L2
    const int lane = t & 63, w = t >> 6;
    const int rl0 = lane & 15;               // A-frag row (local)
    const int hi = (lane >> 4) & 3;
    short8 a[4];
    #pragma unroll
    for (int ks = 0; ks < 4; ks++) {
        int baddr = (rl0 * 256 + ks * 64 + hi * 16) ^ ((rl0 & 7) << 4);
        a[ks] = *(const short8*)((const char*)As + baddr);
    }
    if (FINAL) __syncthreads();              // all a[] loaded before h overwrites As

    const short8* bp = (const short8*)Wp + lane;
    const int c = lane & 15;
    const int rb = hi * 4;                   // C-frag local row base

    #pragma unroll
    for (int i = 0; i < 2; i++) {
        int nt = w * 2 + i;
        f32x4 acc = {0.f, 0.f, 0.f, 0.f};
        short8 b0 = bp[(nt * 4 + 0) * 64];
        short8 b1 = bp[(nt * 4 + 1) * 64];
        short8 b2 = bp[(nt * 4 + 2) * 64];
        short8 b3 = bp[(nt * 4 + 3) * 64];
        acc = __builtin_amdgcn_mfma_f32_16x16x32_bf16(a[0], b0, acc, 0, 0, 0);
        acc = __builtin_amdgcn_mfma_f32_16x16x32_bf16(a[1], b1, acc, 0, 0, 0);
        acc = __builtin_amdgcn_mfma_f32_16x16x32_bf16(a[2], b2, acc, 0, 0, 0);
        acc = __builtin_amdgcn_mfma_f32_16x16x32_bf16(a[3], b3, acc, 0, 0, 0);
        int cc = nt * 16 + c;
        float s = scale[cc], o = offset[cc];
        if (!FINAL) {
            #pragma unroll
            for (int r = 0; r < 4; r++) {
                int rr = row0 + rb + r;
                if (rr < N) {
                    float val = fmaxf(acc[r] * s + o, 0.f);
                    outb[(long)rr * HDIM + cc] = f2bf(val);
                }
            }
        } else {
            #pragma unroll
            for (int r = 0; r < 4; r++) {
                int rloc = rb + r;
                float val = fmaxf(acc[r] * s + o, 0.f);
                int baddr = (rloc * 256 + cc * 2) ^ ((rloc & 7) << 4);
                *(short*)((char*)As + baddr) = f2bf(val);
            }
        }
    }

    if (FINAL) {
        __syncthreads();                     // h tile complete
        short8 a2[4];
        #pragma unroll
        for (int ks = 0; ks < 4; ks++) {
            int baddr = (rl0 * 256 + ks * 64 + hi * 16) ^ ((rl0 & 7) << 4);
            a2[ks] = *(const short8*)((const char*)As + baddr);
        }
        const short8* bp2 = (const short8*)Wp2 + lane;
        int nt = w;
        f32x4 acc = {0.f, 0.f, 0.f, 0.f};
        short8 b0 = bp2[(nt * 4 + 0) * 64];
        short8 b1 = bp2[(nt * 4 + 1) * 64];
        short8 b2 = bp2[(nt * 4 + 2) * 64];
        short8 b3v = bp2[(nt * 4 + 3) * 64];
        acc = __builtin_amdgcn_mfma_f32_16x16x32_bf16(a2[0], b0, acc, 0, 0, 0);
        acc = __builtin_amdgcn_mfma_f32_16x16x32_bf16(a2[1], b1, acc, 0, 0, 0);
        acc = __builtin_amdgcn_mfma_f32_16x16x32_bf16(a2[2], b2, acc, 0, 0, 0);
        acc = __builtin_amdgcn_mfma_f32_16x16x32_bf16(a2[3], b3v, acc, 0, 0, 0);
        int cc = nt * 16 + c;
        float s2 = scale2[cc], o2 = offset2[cc];
        #pragma unroll
        for (int r = 0; r < 4; r++) {
            int rr = row0 + rb + r;
            if (rr < N) outf[(long)rr * 64 + cc] = acc[r] * s2 + o2;
        }
    }
}

extern "C" void kernel_launch(void* const* d_in, const int* in_sizes, int n_in,
                              void* d_out, int out_size, void* d_ws, size_t ws_size,
                              hipStream_t stream) {
    const float* x  = (const float*)d_in[0];
    const int*   ei = (const int*)d_in[1];
    const int E = in_sizes[1] / 2;
    const int* srci = ei;
    const int* dsti = ei + E;

    const float* W0 = (const float*)d_in[2];
    const float* b0 = (const float*)d_in[3];
    const float* g0 = (const float*)d_in[4];
    const float* be0 = (const float*)d_in[5];
    const float* m0 = (const float*)d_in[6];
    const float* v0 = (const float*)d_in[7];
    const float* W1 = (const float*)d_in[8];
    const float* b1 = (const float*)d_in[9];
    const float* g1 = (const float*)d_in[10];
    const float* be1 = (const float*)d_in[11];
    const float* m1 = (const float*)d_in[12];
    const float* v1 = (const float*)d_in[13];
    const float* W2 = (const float*)d_in[14];
    const float* b2 = (const float*)d_in[15];
    const float* g2 = (const float*)d_in[16];
    const float* be2 = (const float*)d_in[17];
    const float* m2 = (const float*)d_in[18];
    const float* v2 = (const float*)d_in[19];
    const float* W3 = (const float*)d_in[20];
    const float* b3 = (const float*)d_in[21];

    const int N = in_sizes[0] / HDIM;
    const int NB = (N + 127) >> 7;                   // buckets of 128 nodes
    float* out = (float*)d_out;

    // ---- workspace layout (16B-aligned sections)
    short* ba = (short*)d_ws;                        // N*128 bf16
    short* bb = ba + (size_t)N * HDIM;               // N*128 bf16
    int* rowptr = (int*)(bb + (size_t)N * HDIM);     // N+1
    int* recs   = rowptr + ((N + 2 + 3) & ~3);       // E records (dstLocal<<16|src)
    unsigned short* csrH = (unsigned short*)(recs + E);  // E u16 srcs
    int* ghist = (int*)(((uintptr_t)(csrH + E) + 63) & ~(uintptr_t)63);  // NBMAX
    int* bucketPtr = ghist + NBMAX;                  // NB+1
    int* bucketCur = bucketPtr + NBMAX + 4;          // NB
    short* Wp0 = (short*)(((uintptr_t)(bucketCur + NBMAX) + 63) & ~(uintptr_t)63);
    short* Wp1  = Wp0 + 16384;
    short* Wp2  = Wp1 + 16384;
    short* Wp3  = Wp2 + 16384;                       // 8192 shorts
    float* scbuf = (float*)(Wp3 + 8192);             // 4 layers x 256 floats (scale|offset)

    const int layerBlocks = (N + 15) / 16;
    const int nElem = N * HDIM;
    int cvtBlocks = (nElem / 4 + 255) / 256; if (cvtBlocks > 2048) cvtBlocks = 2048;

    // ---- prep: pack weights+scales+zero ghist FIRST (stream order), then CSR build
    prep_all<<<30, 256, 0, stream>>>(Wp0, Wp1, Wp2, Wp3, W0, W1, W2, W3, scbuf, ghist,
                                     b0, g0, be0, m0, v0,
                                     b1, g1, be1, m1, v1,
                                     b2, g2, be2, m2, v2, b3);
    cvt_bf16<<<cvtBlocks, 256, 0, stream>>>(ba, x, nElem);
    hist_buckets<<<256, 256, 0, stream>>>(ghist, dsti, E, NB);
    scan_buckets<<<1, 64, 0, stream>>>(bucketPtr, bucketCur, ghist, NB, rowptr, N, E);
    scatter_recs<<<(E + 4095) / 4096, 256, 0, stream>>>(recs, bucketCur, srci, dsti, E, NB);
    build_csr_local<<<NB, 256, 0, stream>>>(csrH, rowptr, recs, bucketPtr, N);

    // ---- 3 fused layers (last one also applies W3 -> fp32 out)
    gin_layer<false><<<layerBlocks, 256, 0, stream>>>(
        bb, nullptr, ba, rowptr, csrH, Wp0, scbuf + 0, scbuf + 128,
        nullptr, nullptr, nullptr, N);
    gin_layer<false><<<layerBlocks, 256, 0, stream>>>(
        ba, nullptr, bb, rowptr, csrH, Wp1, scbuf + 256, scbuf + 384,
        nullptr, nullptr, nullptr, N);
    gin_layer<true><<<layerBlocks, 256, 0, stream>>>(
        nullptr, out, ba, rowptr, csrH, Wp2, scbuf + 512, scbuf + 640,
        Wp3, scbuf + 768, scbuf + 896, N);
}